// Round 7
// baseline (542.702 us; speedup 1.0000x reference)
//
#include <hip/hip_runtime.h>
#include <stdint.h>

namespace {

constexpr int B_ = 2, T_ = 2048, C_ = 2048, H_ = 16, D_ = 128;
constexpr int R_ = B_ * T_;                 // 4096 token rows (b*T + t)
constexpr float EPSF = 1e-5f;
constexpr float INV_SQRT_D = 0.08838834764831845f;   // 1/sqrt(128)
constexpr float LOG2E = 1.4426950408889634f;
constexpr float LOG2_127 = 6.988684686772166f;

// ---- workspace layout (bytes) ----
constexpr size_t OFF_WSUM = 0;                                   // double[4]
constexpr size_t OFF_SW   = 64;                                  // float[4]
constexpr size_t OFF_WT   = 256;                                 // int8[4][C*C] ternary
constexpr size_t OFF_XQ   = OFF_WT   + (size_t)4 * C_ * C_;      // int8[R*C]
constexpr size_t OFF_SX   = OFF_XQ   + (size_t)R_ * C_;          // float[R]
constexpr size_t OFF_QKV  = OFF_SX   + (size_t)R_ * 4;           // int8[3][B*H*T*D]
constexpr size_t OFF_SQKV = OFF_QKV  + (size_t)3 * R_ * C_;      // float[3][B*H*T]
constexpr size_t OFF_YQ   = OFF_SQKV + (size_t)3 * R_ * H_ * 4;  // int8[R*C]
constexpr size_t OFF_SY   = OFF_YQ   + (size_t)R_ * C_;          // float[R*H]
constexpr size_t OFF_OUTP = OFF_SY   + (size_t)R_ * H_ * 4;      // float[R*C]
// vT (bf16 hi/lo interleaved PV-fragment layout, 33.55 MB) aliases OUTP (33.55 MB):
// dead before outproj writes outp (stream-ordered), so no extra workspace.
constexpr size_t OFF_VT   = OFF_OUTP;

typedef int   i32x4 __attribute__((ext_vector_type(4)));
typedef short s16x8 __attribute__((ext_vector_type(8)));
typedef float f32x4 __attribute__((ext_vector_type(4)));
typedef unsigned int u32x4 __attribute__((ext_vector_type(4)));

__device__ __forceinline__ i32x4 mfma_i8(i32x4 a, i32x4 b, i32x4 c) {
  return __builtin_amdgcn_mfma_i32_16x16x64_i8(a, b, c, 0, 0, 0);
}
__device__ __forceinline__ f32x4 mfma_bf16(s16x8 a, s16x8 b, f32x4 c) {
  return __builtin_amdgcn_mfma_f32_16x16x32_bf16(a, b, c, 0, 0, 0);
}

// async global->LDS DMA, 16B per lane; LDS dest = wave-uniform base + lane*16
__device__ __forceinline__ void dma16(const void* g, void* l) {
  __builtin_amdgcn_global_load_lds(
      (const __attribute__((address_space(1))) void*)g,
      (__attribute__((address_space(3))) void*)l, 16, 0, 0);
}

#if __has_builtin(__builtin_amdgcn_exp2f)
__device__ __forceinline__ float fast_exp2(float x) { return __builtin_amdgcn_exp2f(x); }
#else
__device__ __forceinline__ float fast_exp2(float x) { return exp2f(x); }
#endif

// RTNE float->bf16 bits (matches numpy RTNE)
__device__ __forceinline__ short f2bf(float f) {
  union { float f; uint32_t u; } v; v.f = f;
  uint32_t r = v.u + 0x7fffu + ((v.u >> 16) & 1u);
  return (short)(r >> 16);
}
__device__ __forceinline__ float bf2f(short h) {
  union { uint32_t u; float f; } v; v.u = ((uint32_t)(uint16_t)h) << 16;
  return v.f;
}

// ---------------- mean(|W|) for the 4 weight matrices (double accum) ----------------
__global__ __launch_bounds__(256) void wabs_sum_kernel(
    const float* __restrict__ W0, const float* __restrict__ W1,
    const float* __restrict__ W2, const float* __restrict__ W3,
    double* __restrict__ wsum)
{
  const int w   = blockIdx.x >> 6;
  const int blk = blockIdx.x & 63;
  const float* W = (w == 0) ? W0 : (w == 1) ? W1 : (w == 2) ? W2 : W3;
  const int n = C_ * C_;
  double s = 0.0;
  for (int i = blk * 256 + (int)threadIdx.x; i < n; i += 64 * 256)
    s += (double)fabsf(W[i]);
  __shared__ double sm[256];
  sm[threadIdx.x] = s;
  __syncthreads();
  for (int o = 128; o > 0; o >>= 1) {
    if ((int)threadIdx.x < o) sm[threadIdx.x] += sm[threadIdx.x + o];
    __syncthreads();
  }
  if (threadIdx.x == 0) atomicAdd(&wsum[w], sm[0]);
}

// ---------------- ternary weight quant ----------------
__global__ __launch_bounds__(256) void wquant_kernel(
    const float* __restrict__ W0, const float* __restrict__ W1,
    const float* __restrict__ W2, const float* __restrict__ W3,
    const double* __restrict__ wsum, int8_t* __restrict__ Wt, float* __restrict__ sw)
{
  const int w = blockIdx.x >> 10;
  const float* W = (w == 0) ? W0 : (w == 1) ? W1 : (w == 2) ? W2 : W3;
  const int n = C_ * C_;
  const float s = fmaxf((float)(wsum[w] * (1.0 / (double)n)), EPSF);
  int8_t* dst = Wt + (size_t)w * n;
  const int base = (blockIdx.x & 1023) * 256 + (int)threadIdx.x;
  for (int i = base; i < n; i += 1024 * 256) {
    float t = rintf(W[i] / s);
    t = fminf(fmaxf(t, -1.f), 1.f);
    dst[i] = (int8_t)t;
  }
  if (base == 0) sw[w] = s;
}

// ---------------- per-token act_quant of x ----------------
__global__ __launch_bounds__(256) void xquant_kernel(
    const float* __restrict__ x, int8_t* __restrict__ xq, float* __restrict__ sx)
{
  const int r = blockIdx.x;
  const float* xr = x + (size_t)r * C_;
  float am = 0.f;
  for (int j = threadIdx.x; j < C_; j += 256) am = fmaxf(am, fabsf(xr[j]));
  __shared__ float sm[256];
  sm[threadIdx.x] = am;
  __syncthreads();
  for (int o = 128; o > 0; o >>= 1) {
    if ((int)threadIdx.x < o) sm[threadIdx.x] = fmaxf(sm[threadIdx.x], sm[threadIdx.x + o]);
    __syncthreads();
  }
  const float m = fmaxf(sm[0], EPSF);
  const float scale = 127.f / m;
  for (int j = threadIdx.x; j < C_; j += 256) {
    float q = fminf(fmaxf(rintf(xr[j] * scale), -128.f), 127.f);
    xq[(size_t)r * C_ + j] = (int8_t)q;
  }
  if (threadIdx.x == 0) sx[r] = m / 127.f;
}

// ---------------- q/k/v projection v2: counted-vmcnt triple-buffer (T3/T4) ----------
// R6: proj is the largest unprofiled kernel (<=155us by top-5 bound, MFMA floor ~7us).
// Its old __syncthreads drained vmcnt(0) on the just-issued prefetch every K-chunk —
// the exact stall v13 removed from attn. Same recipe: 3 buffers, stage(kc+1) ->
// s_waitcnt vmcnt(4) (own 4 newest stay in flight; chunk-kc's 4 drained) -> raw
// s_barrier. WAR safe by the v13 argument (buffer (kc+1)%3 readers finished before
// barrier kc-1). MFMA/quant math byte-identical.
__global__ __launch_bounds__(256) void proj_mfma_kernel(
    const int8_t* __restrict__ xq, const float* __restrict__ sx,
    const int8_t* __restrict__ Wt, const float* __restrict__ sw4,
    int8_t* __restrict__ qkv, float* __restrict__ sqkv)
{
  const int h    = blockIdx.x;
  const int r0   = blockIdx.y * 128;
  const int wsel = blockIdx.z;
  const int tid  = (int)threadIdx.x;
  const int wv   = tid >> 6;
  const int lane = tid & 63;
  const int quad = lane >> 4;
  const int l15  = lane & 15;
  const int rh   = wv >> 1, ch = wv & 1;
  const int8_t* Wm = Wt + (size_t)wsel * C_ * C_;

  __shared__ __align__(16) char As[3][8192];   // 512 slots x 16B, swizzled
  __shared__ __align__(16) char Bs[3][8192];
  __shared__ int rmaxs[128];
  if (tid < 128) rmaxs[tid] = 0;

  const int s0a   = wv * 128;
  const int rowA0 = (s0a + lane) >> 2;
  const int qdA0  = ((s0a + lane) & 3) ^ (rowA0 & 3);
  const int rowA1 = (s0a + 64 + lane) >> 2;
  const int qdA1  = ((s0a + 64 + lane) & 3) ^ (rowA1 & 3);

  auto stage = [&](int bf, int k0) {
    dma16(xq + (size_t)(r0 + rowA0) * C_ + k0 + qdA0 * 16, &As[bf][(s0a) * 16]);
    dma16(xq + (size_t)(r0 + rowA1) * C_ + k0 + qdA1 * 16, &As[bf][(s0a + 64) * 16]);
    dma16(Wm + (size_t)(h * 128 + rowA0) * C_ + k0 + qdA0 * 16, &Bs[bf][(s0a) * 16]);
    dma16(Wm + (size_t)(h * 128 + rowA1) * C_ + k0 + qdA1 * 16, &Bs[bf][(s0a + 64) * 16]);
  };

  i32x4 acc[4][4];
  #pragma unroll
  for (int i = 0; i < 4; ++i)
    #pragma unroll
    for (int j = 0; j < 4; ++j) acc[i][j] = i32x4{0, 0, 0, 0};

  stage(0, 0);
  int bc = 0, bn = 1;
  for (int kc = 0; kc < 32; ++kc) {
    if (kc + 1 < 32) {
      stage(bn, (kc + 1) * 64);
      asm volatile("s_waitcnt vmcnt(4)" ::: "memory");   // chunk-kc DMAs done
    } else {
      asm volatile("s_waitcnt vmcnt(0)" ::: "memory");
    }
    __builtin_amdgcn_s_barrier();                        // all waves' chunk-kc done
    asm volatile("" ::: "memory");                       // pin reads after barrier

    const char* Ab = As[bc];
    const char* Bb = Bs[bc];
    i32x4 a[4], b[4];
    #pragma unroll
    for (int rt = 0; rt < 4; ++rt) {
      const int row = rh * 64 + rt * 16 + l15;
      a[rt] = *(const i32x4*)(Ab + (row * 4 + (quad ^ (row & 3))) * 16);
    }
    #pragma unroll
    for (int ct = 0; ct < 4; ++ct) {
      const int col = ch * 64 + ct * 16 + l15;
      b[ct] = *(const i32x4*)(Bb + (col * 4 + (quad ^ (col & 3))) * 16);
    }
    #pragma unroll
    for (int rt = 0; rt < 4; ++rt)
      #pragma unroll
      for (int ct = 0; ct < 4; ++ct)
        acc[rt][ct] = mfma_i8(a[rt], b[ct], acc[rt][ct]);

    bc = bn; bn = (bn == 2) ? 0 : bn + 1;
  }

  #pragma unroll
  for (int rt = 0; rt < 4; ++rt)
    #pragma unroll
    for (int r = 0; r < 4; ++r) {
      int m = 0;
      #pragma unroll
      for (int ct = 0; ct < 4; ++ct) {
        int v = acc[rt][ct][r];
        int av = v < 0 ? -v : v;
        m = m > av ? m : av;
      }
      #pragma unroll
      for (int mm = 1; mm < 16; mm <<= 1) {
        int o = __shfl_xor(m, mm, 64);
        m = m > o ? m : o;
      }
      if (l15 == 0) atomicMax(&rmaxs[rh * 64 + rt * 16 + quad * 4 + r], m);
    }
  __syncthreads();

  const float swv = sw4[wsel];
  #pragma unroll
  for (int rt = 0; rt < 4; ++rt)
    #pragma unroll
    for (int r = 0; r < 4; ++r) {
      const int rowl = rh * 64 + rt * 16 + quad * 4 + r;
      const int rglob = r0 + rowl;
      const int mN = rmaxs[rowl];
      const float qscale = (mN > 0) ? 127.f / (float)mN : 0.f;
      const int bb = rglob >> 11;
      const int tt = rglob & (T_ - 1);
      const size_t obase = ((size_t)(bb * H_ + h) * T_ + tt) * D_;
      #pragma unroll
      for (int ct = 0; ct < 4; ++ct) {
        const int col = ch * 64 + ct * 16 + l15;
        float q = rintf((float)acc[rt][ct][r] * qscale);
        q = fminf(fmaxf(q, -128.f), 127.f);
        qkv[(size_t)wsel * R_ * C_ + obase + col] = (int8_t)q;
      }
      if (ch == 0 && l15 == 0) {
        float maxq = (float)mN * sx[rglob] * swv;
        sqkv[(size_t)wsel * R_ * H_ + (size_t)(bb * H_ + h) * T_ + tt] =
            fmaxf(maxq, EPSF) / 127.f;
      }
    }
}

// ---------------- V dequant+transpose: int8 [bh][t][d] -> PV-fragment layout ---------
// Output vT: per (bh, d, 32-key chunk c) one 128B row of 8 x 16B segs.
//   seg ((2g + d) & 7)     = hi bf16 of keys { kt*16 + g*4 + r : kt in 0..1, r in 0..3 }
//   seg ((2g + 1 + d) & 7) = lo bf16 of the same keys
// Rotation by d makes every wave64 ds_read_b128 conflict-free (each consecutive
// 8-lane group hits 8 distinct 16B slots). Unchanged from v11/v12 (verified).
__global__ __launch_bounds__(256) void vtrans_kernel(
    const int8_t* __restrict__ vq, const float* __restrict__ sv,
    short* __restrict__ vT)
{
  const int bh = blockIdx.y;
  const int s0 = blockIdx.x * 64;
  const int tid = (int)threadIdx.x;
  __shared__ __align__(16) int8_t Vs[64][144];
  __shared__ float svs[64];
  const int8_t* vbase = vq + ((size_t)bh * T_ + s0) * D_;
  #pragma unroll
  for (int it = 0; it < 2; ++it) {
    int idx = tid + it * 256;
    int row = idx >> 3, seg = idx & 7;
    *(uint4*)(&Vs[row][seg * 16]) = *(const uint4*)(vbase + row * 128 + seg * 16);
  }
  if (tid < 64) svs[tid] = sv[(size_t)bh * T_ + s0 + tid];
  __syncthreads();
  const int d    = tid >> 1;
  const int half = tid & 1;            // which 32-key chunk within this block
  const int kh   = half * 32;
  uint32_t oh[16], ol[16];
  #pragma unroll
  for (int i = 0; i < 32; i += 2) {
    const int k0 = kh + i, k1 = kh + i + 1;
    float v0 = (float)(int)Vs[k0][d] * svs[k0];
    float v1 = (float)(int)Vs[k1][d] * svs[k1];
    short h0 = f2bf(v0), h1 = f2bf(v1);
    short l0 = f2bf(v0 - bf2f(h0)), l1 = f2bf(v1 - bf2f(h1));
    oh[i >> 1] = (uint32_t)(uint16_t)h0 | ((uint32_t)(uint16_t)h1 << 16);
    ol[i >> 1] = (uint32_t)(uint16_t)l0 | ((uint32_t)(uint16_t)l1 << 16);
  }
  const int c = (s0 >> 5) + half;      // global 32-key chunk index (0..63)
  char* out = (char*)vT + ((((size_t)bh * 128 + d) * 64 + (size_t)c) << 7);
  const int par = d & 7;
  #pragma unroll
  for (int g = 0; g < 4; ++g) {
    uint4 hi, lo;
    hi.x = oh[2 * g];     hi.y = oh[2 * g + 1];
    hi.z = oh[2 * g + 8]; hi.w = oh[2 * g + 9];
    lo.x = ol[2 * g];     lo.y = ol[2 * g + 1];
    lo.z = ol[2 * g + 8]; lo.w = ol[2 * g + 9];
    *(uint4*)(out + (((2 * g + par) & 7) << 4))     = hi;
    *(uint4*)(out + (((2 * g + 1 + par) & 7) << 4)) = lo;
  }
}

// ---------------- fused attention v13: counted-vmcnt pipeline (T3/T4) ----------------
// UNCHANGED from R5's measured-best (155.0us, Mfma 28.6 / VALU 37.2). See R5 notes.
__global__ __launch_bounds__(256, 2) void attn_mfma_kernel(
    const int8_t* __restrict__ qq, const int8_t* __restrict__ kq,
    const float* __restrict__ sq, const float* __restrict__ sk,
    const short* __restrict__ vT,
    int8_t* __restrict__ yq, float* __restrict__ sy)
{
  const int bh  = blockIdx.x;
  const int t0  = blockIdx.y * 128;
  const int tid = (int)threadIdx.x;
  const int w    = tid >> 6;           // 4 waves
  const int lane = tid & 63;
  const int quad = lane >> 4;
  const int l15  = lane & 15;

  // LDS: K bufs 3x4KB [0,12288); V bufs 3x16KB [12288,61440); sks [61440,69632)
  __shared__ __align__(16) char smem[69632];
  float* sks = (float*)(smem + 61440);

  const int qrow0 = t0 + 32 * w;

  const int8_t* kq_bh = kq + (size_t)bh * T_ * D_;
  const char*   vb    = (const char*)vT + ((size_t)bh << 20);

  const int kslot = w * 64 + lane;               // 0..255
  const int kkey  = kslot >> 3;                  // 0..31
  const int ksrc  = ((kslot & 7) ^ (kkey & 7)) * 16;
  auto stageK = [&](int buf, int cc) {
    dma16(kq_bh + (size_t)(cc * 32 + kkey) * 128 + ksrc,
          smem + buf * 4096 + (w * 64) * 16);
  };

  const size_t vlane = (size_t)(w * 32 + (lane >> 3)) * 8192 + (size_t)((lane & 7) * 16);
  auto stageV = [&](int buf, int cc) {
    char* dst = smem + 12288 + buf * 16384 + (w * 32) * 128;
    const char* src = vb + vlane + (size_t)cc * 128;
    #pragma unroll
    for (int j = 0; j < 4; ++j)
      dma16(src + (size_t)(j * 8) * 8192, dst + j * 1024);
  };

  {
    const float* skg = sk + (size_t)bh * T_;
    dma16(skg + (w * 2 + 0) * 256 + lane * 4, smem + 61440 + (w * 2 + 0) * 1024);
    dma16(skg + (w * 2 + 1) * 256 + lane * 4, smem + 61440 + (w * 2 + 1) * 1024);
  }
  stageK(0, 0);
  stageV(0, 0);

  i32x4 qf[2][2];
  #pragma unroll
  for (int qt = 0; qt < 2; ++qt)
    #pragma unroll
    for (int hf = 0; hf < 2; ++hf)
      qf[qt][hf] = *(const i32x4*)(qq + ((size_t)bh * T_ + qrow0 + qt * 16 + l15) * D_ +
                                   hf * 64 + quad * 16);
  float f0[2];
  #pragma unroll
  for (int qt = 0; qt < 2; ++qt)
    f0[qt] = sq[(size_t)bh * T_ + qrow0 + qt * 16 + l15] * INV_SQRT_D;

  __syncthreads();   // sks + chunk-0 visible before pass 1

  const int8_t* kqb = kq_bh + (size_t)(l15 * D_ + quad * 16);

  // ---- pass 1: exact rowmax of c*sk; global K stream, sk from LDS, no barriers ----
  float rx[2][4];
  #pragma unroll
  for (int qt = 0; qt < 2; ++qt)
    #pragma unroll
    for (int r = 0; r < 4; ++r) rx[qt][r] = -3e38f;

  for (int s0 = 0; s0 < T_; s0 += 64) {
    #pragma unroll
    for (int kt = 0; kt < 4; ++kt) {
      const f32x4 skv = *(const f32x4*)(sks + s0 + kt * 16 + quad * 4);
      const i32x4 ka = *(const i32x4*)(kqb + (size_t)(s0 + kt * 16) * D_);
      const i32x4 kb = *(const i32x4*)(kqb + (size_t)(s0 + kt * 16) * D_ + 64);
      #pragma unroll
      for (int qt = 0; qt < 2; ++qt) {
        i32x4 c = i32x4{0, 0, 0, 0};
        c = mfma_i8(ka, qf[qt][0], c);
        c = mfma_i8(kb, qf[qt][1], c);
        #pragma unroll
        for (int r = 0; r < 4; ++r)
          rx[qt][r] = fmaxf(rx[qt][r], (float)c[r] * skv[r]);
      }
    }
  }
  float f1[2], g[2];
  #pragma unroll
  for (int qt = 0; qt < 2; ++qt) {
    float m = fmaxf(fmaxf(rx[qt][0], rx[qt][1]), fmaxf(rx[qt][2], rx[qt][3]));
    m = fmaxf(m, __shfl_xor(m, 16, 64));
    m = fmaxf(m, __shfl_xor(m, 32, 64));
    f1[qt] = f0[qt] * LOG2E;
    g[qt]  = LOG2_127 - (m * f0[qt]) * LOG2E;
  }

  // ---- pass 2: quantized softmax (in-register weights) + PV, 64 x 32-key chunks ----
  float zac[2][4] = {};
  f32x4 yacc[2][8];
  #pragma unroll
  for (int qt = 0; qt < 2; ++qt)
    #pragma unroll
    for (int dt = 0; dt < 8; ++dt) yacc[qt][dt] = f32x4{0.f, 0.f, 0.f, 0.f};

  const int seg_hi = ((2 * quad + l15) & 7) << 4;
  const int seg_lo = ((2 * quad + 1 + l15) & 7) << 4;

  int bc = 0, bn = 1;
  for (int c = 0; c < 64; ++c) {
    const int s0k = c * 32;
    if (c + 1 < 64) {
      stageK(bn, c + 1);
      stageV(bn, c + 1);
      asm volatile("s_waitcnt vmcnt(5)" ::: "memory");   // own chunk-c DMAs done
    } else {
      asm volatile("s_waitcnt vmcnt(0)" ::: "memory");
    }
    __builtin_amdgcn_s_barrier();                        // all waves' chunk-c done
    asm volatile("" ::: "memory");                       // pin reads after barrier

    const char* Kb = smem + bc * 4096;
    uint32_t wdw[2][2][2];
    #pragma unroll
    for (int kt = 0; kt < 2; ++kt) {
      const f32x4 skv = *(const f32x4*)(sks + s0k + kt * 16 + quad * 4);
      const int key = kt * 16 + l15;
      const i32x4 ka = *(const i32x4*)(Kb + key * 128 + ((quad ^ (key & 7)) << 4));
      const i32x4 kb = *(const i32x4*)(Kb + key * 128 + (((quad + 4) ^ (key & 7)) << 4));
      #pragma unroll
      for (int qt = 0; qt < 2; ++qt) {
        i32x4 cc = i32x4{0, 0, 0, 0};
        cc = mfma_i8(ka, qf[qt][0], cc);
        cc = mfma_i8(kb, qf[qt][1], cc);
        float wq_[4];
        #pragma unroll
        for (int r = 0; r < 4; ++r) {
          float t = (float)cc[r] * skv[r];
          float wu = fast_exp2(fmaf(t, f1[qt], g[qt]));  // = 127*exp(s-m)
          zac[qt][r] += wu;
          wq_[r] = rintf(wu);                            // integer in [0,127]
        }
        wdw[qt][kt][0] = (__float_as_uint(wq_[0]) >> 16) |
                         (__float_as_uint(wq_[1]) & 0xffff0000u);
        wdw[qt][kt][1] = (__float_as_uint(wq_[2]) >> 16) |
                         (__float_as_uint(wq_[3]) & 0xffff0000u);
      }
    }

    s16x8 wf[2];
    #pragma unroll
    for (int qt = 0; qt < 2; ++qt) {
      u32x4 tw;
      tw[0] = wdw[qt][0][0]; tw[1] = wdw[qt][0][1];
      tw[2] = wdw[qt][1][0]; tw[3] = wdw[qt][1][1];
      wf[qt] = __builtin_bit_cast(s16x8, tw);
    }

    const char* Vc = smem + 12288 + bc * 16384;
    __builtin_amdgcn_s_setprio(1);
    #pragma unroll
    for (int dt = 0; dt < 8; ++dt) {
      const char* rowp = Vc + (dt * 16 + l15) * 128;
      const s16x8 vh = *(const s16x8*)(rowp + seg_hi);
      const s16x8 vl = *(const s16x8*)(rowp + seg_lo);
      yacc[0][dt] = mfma_bf16(wf[0], vh, yacc[0][dt]);
      yacc[0][dt] = mfma_bf16(wf[0], vl, yacc[0][dt]);
      yacc[1][dt] = mfma_bf16(wf[1], vh, yacc[1][dt]);
      yacc[1][dt] = mfma_bf16(wf[1], vl, yacc[1][dt]);
    }
    __builtin_amdgcn_s_setprio(0);

    bc = bn; bn = (bn == 2) ? 0 : bn + 1;
  }

  // ---- epilogue: z reduce over quads, transpose to yacc's row layout, quantize ----
  float zq[2];
  #pragma unroll
  for (int qt = 0; qt < 2; ++qt) {
    float z = (zac[qt][0] + zac[qt][1]) + (zac[qt][2] + zac[qt][3]);
    z += __shfl_xor(z, 16, 64);
    z += __shfl_xor(z, 32, 64);
    zq[qt] = z;                       // all lanes: 127*Z for q = l15
  }

  const int b = bh >> 4;
  const int h = bh & 15;
  #pragma unroll
  for (int qt = 0; qt < 2; ++qt)
    #pragma unroll
    for (int r = 0; r < 4; ++r) {
      const float zr = __shfl(zq[qt], quad * 4 + r, 64);   // z for q = quad*4+r
      float ym = 0.f;
      #pragma unroll
      for (int dt = 0; dt < 8; ++dt) ym = fmaxf(ym, fabsf(yacc[qt][dt][r]));
      #pragma unroll
      for (int mm = 1; mm < 16; mm <<= 1) ym = fmaxf(ym, __shfl_xor(ym, mm, 64));
      const float invz = 1.f / zr;
      const float ymt = fmaxf(ym * invz, EPSF);
      const float fs = 127.f / ymt;
      const int tglob = t0 + 32 * w + qt * 16 + quad * 4 + r;
      const size_t rowbase = ((size_t)(b * T_ + tglob)) * C_ + h * D_;
      #pragma unroll
      for (int dt = 0; dt < 8; ++dt) {
        float yv = yacc[qt][dt][r] * invz;
        float qv = fminf(fmaxf(rintf(yv * fs), -128.f), 127.f);
        yq[rowbase + dt * 16 + l15] = (int8_t)qv;
      }
      if (l15 == 0)
        sy[(size_t)(b * T_ + tglob) * H_ + h] = ymt / 127.f;
    }
}

// ---------------- output projection v3: counted-vmcnt triple-buffer (T3/T4) ----------
// R6: same transplant as proj v2. 3 dma/wave per chunk -> vmcnt(3). Math identical.
__global__ __launch_bounds__(256) void outproj_mfma_kernel(
    const int8_t* __restrict__ yq, const float* __restrict__ sy,
    const int8_t* __restrict__ Wt, const float* __restrict__ sw4,
    float* __restrict__ outp)
{
  const int n0  = blockIdx.x * 64;
  const int r0  = blockIdx.y * 128;
  const int tid = (int)threadIdx.x;
  const int wv   = tid >> 6;
  const int lane = tid & 63;
  const int quad = lane >> 4;
  const int l15  = lane & 15;
  const int rh   = wv >> 1, ch = wv & 1;
  const int8_t* Wm = Wt + (size_t)3 * C_ * C_;

  __shared__ __align__(16) char As[3][8192];   // 512 slots x 16B, swizzled
  __shared__ __align__(16) char Bs[3][4096];   // 256 slots x 16B, swizzled
  __shared__ float sYs[128][16];
  for (int idx = tid; idx < 128 * 16; idx += 256)
    sYs[idx >> 4][idx & 15] = sy[(size_t)(r0 + (idx >> 4)) * H_ + (idx & 15)];

  const int s0a   = wv * 128;
  const int rowA0 = (s0a + lane) >> 2;
  const int qdA0  = ((s0a + lane) & 3) ^ (rowA0 & 3);
  const int rowA1 = (s0a + 64 + lane) >> 2;
  const int qdA1  = ((s0a + 64 + lane) & 3) ^ (rowA1 & 3);
  const int sb    = wv * 64 + lane;
  const int colB  = sb >> 2;
  const int qdB   = (sb & 3) ^ (colB & 3);

  auto stage = [&](int bf, int k0) {
    dma16(yq + (size_t)(r0 + rowA0) * C_ + k0 + qdA0 * 16, &As[bf][(s0a) * 16]);
    dma16(yq + (size_t)(r0 + rowA1) * C_ + k0 + qdA1 * 16, &As[bf][(s0a + 64) * 16]);
    dma16(Wm + (size_t)(n0 + colB) * C_ + k0 + qdB * 16, &Bs[bf][(wv * 64) * 16]);
  };

  i32x4 iacc[4][2];
  f32x4 facc[4][2];
  #pragma unroll
  for (int i = 0; i < 4; ++i)
    #pragma unroll
    for (int j = 0; j < 2; ++j) { iacc[i][j] = i32x4{0,0,0,0}; facc[i][j] = f32x4{0.f,0.f,0.f,0.f}; }

  stage(0, 0);
  int bc = 0, bn = 1;
  for (int kc = 0; kc < 32; ++kc) {
    if (kc + 1 < 32) {
      stage(bn, (kc + 1) * 64);
      asm volatile("s_waitcnt vmcnt(3)" ::: "memory");   // chunk-kc DMAs done
    } else {
      asm volatile("s_waitcnt vmcnt(0)" ::: "memory");
    }
    __builtin_amdgcn_s_barrier();
    asm volatile("" ::: "memory");

    const char* Ab = As[bc];
    const char* Bb = Bs[bc];
    i32x4 a[4], b[2];
    #pragma unroll
    for (int rt = 0; rt < 4; ++rt) {
      const int row = rh * 64 + rt * 16 + l15;
      a[rt] = *(const i32x4*)(Ab + (row * 4 + (quad ^ (row & 3))) * 16);
    }
    #pragma unroll
    for (int ct = 0; ct < 2; ++ct) {
      const int col = ch * 32 + ct * 16 + l15;
      b[ct] = *(const i32x4*)(Bb + (col * 4 + (quad ^ (col & 3))) * 16);
    }
    #pragma unroll
    for (int rt = 0; rt < 4; ++rt)
      #pragma unroll
      for (int ct = 0; ct < 2; ++ct)
        iacc[rt][ct] = mfma_i8(a[rt], b[ct], iacc[rt][ct]);
    if (kc & 1) {
      const int hd = kc >> 1;
      #pragma unroll
      for (int rt = 0; rt < 4; ++rt)
        #pragma unroll
        for (int r = 0; r < 4; ++r) {
          const float s = sYs[rh * 64 + rt * 16 + quad * 4 + r][hd];
          #pragma unroll
          for (int ct = 0; ct < 2; ++ct)
            facc[rt][ct][r] += (float)iacc[rt][ct][r] * s;
        }
      #pragma unroll
      for (int rt = 0; rt < 4; ++rt)
        #pragma unroll
        for (int ct = 0; ct < 2; ++ct) iacc[rt][ct] = i32x4{0,0,0,0};
    }

    bc = bn; bn = (bn == 2) ? 0 : bn + 1;
  }
  const float swp = sw4[3];
  #pragma unroll
  for (int rt = 0; rt < 4; ++rt)
    #pragma unroll
    for (int r = 0; r < 4; ++r) {
      const int rowl = rh * 64 + rt * 16 + quad * 4 + r;
      #pragma unroll
      for (int ct = 0; ct < 2; ++ct)
        outp[(size_t)(r0 + rowl) * C_ + n0 + ch * 32 + ct * 16 + l15] =
            facc[rt][ct][r] * swp;
    }
}

// ---------------- final per-token act_quant ----------------
__global__ __launch_bounds__(256) void final_quant_kernel(
    const float* __restrict__ outp, float* __restrict__ out)
{
  const int r = blockIdx.x;
  const float* xr = outp + (size_t)r * C_;
  float am = 0.f;
  for (int j = threadIdx.x; j < C_; j += 256) am = fmaxf(am, fabsf(xr[j]));
  __shared__ float sm[256];
  sm[threadIdx.x] = am;
  __syncthreads();
  for (int o = 128; o > 0; o >>= 1) {
    if ((int)threadIdx.x < o) sm[threadIdx.x] = fmaxf(sm[threadIdx.x], sm[threadIdx.x + o]);
    __syncthreads();
  }
  const float m = fmaxf(sm[0], EPSF);
  const float scale = 127.f / m;
  const float inv = m / 127.f;
  for (int j = threadIdx.x; j < C_; j += 256) {
    float q = fminf(fmaxf(rintf(xr[j] * scale), -128.f), 127.f);
    out[(size_t)r * C_ + j] = q * inv;
  }
}

} // namespace

extern "C" void kernel_launch(void* const* d_in, const int* in_sizes, int n_in,
                              void* d_out, int out_size, void* d_ws, size_t ws_size,
                              hipStream_t stream)
{
  (void)in_sizes; (void)n_in; (void)out_size; (void)ws_size;
  const float* x  = (const float*)d_in[0];
  const float* W0 = (const float*)d_in[1];
  const float* W1 = (const float*)d_in[2];
  const float* W2 = (const float*)d_in[3];
  const float* W3 = (const float*)d_in[4];

  char* ws = (char*)d_ws;
  double* wsum = (double*)(ws + OFF_WSUM);
  float*  swv  = (float*) (ws + OFF_SW);
  int8_t* Wt   = (int8_t*)(ws + OFF_WT);
  int8_t* xq   = (int8_t*)(ws + OFF_XQ);
  float*  sx   = (float*) (ws + OFF_SX);
  int8_t* qkv  = (int8_t*)(ws + OFF_QKV);
  float*  sqkv = (float*) (ws + OFF_SQKV);
  int8_t* yqp  = (int8_t*)(ws + OFF_YQ);
  float*  syp  = (float*) (ws + OFF_SY);
  float*  outp = (float*) (ws + OFF_OUTP);
  short*  vT   = (short*) (ws + OFF_VT);           // aliases outp

  hipMemsetAsync(d_ws, 0, 256, stream);
  hipLaunchKernelGGL(wabs_sum_kernel, dim3(256), dim3(256), 0, stream, W0, W1, W2, W3, wsum);
  hipLaunchKernelGGL(wquant_kernel, dim3(4096), dim3(256), 0, stream, W0, W1, W2, W3, wsum, Wt, swv);
  hipLaunchKernelGGL(xquant_kernel, dim3(R_), dim3(256), 0, stream, x, xq, sx);
  hipLaunchKernelGGL(proj_mfma_kernel, dim3(H_, R_ / 128, 3), dim3(256), 0, stream,
                     xq, sx, Wt, swv, qkv, sqkv);
  hipLaunchKernelGGL(vtrans_kernel, dim3(T_ / 64, B_ * H_), dim3(256), 0, stream,
                     qkv + (size_t)2 * R_ * C_, sqkv + (size_t)2 * R_ * H_, vT);
  hipLaunchKernelGGL(attn_mfma_kernel, dim3(B_ * H_, T_ / 128), dim3(256), 0, stream,
                     qkv, qkv + (size_t)R_ * C_,
                     sqkv, sqkv + (size_t)R_ * H_,
                     vT, yqp, syp);
  hipLaunchKernelGGL(outproj_mfma_kernel, dim3(C_ / 64, R_ / 128), dim3(256), 0, stream,
                     yqp, syp, Wt, swv, outp);
  hipLaunchKernelGGL(final_quant_kernel, dim3(R_), dim3(256), 0, stream, outp, (float*)d_out);
}

// Round 8
// 537.467 us; speedup vs baseline: 1.0097x; 1.0097x over previous
//
#include <hip/hip_runtime.h>
#include <stdint.h>

namespace {

constexpr int B_ = 2, T_ = 2048, C_ = 2048, H_ = 16, D_ = 128;
constexpr int R_ = B_ * T_;                 // 4096 token rows (b*T + t)
constexpr float EPSF = 1e-5f;
constexpr float INV_SQRT_D = 0.08838834764831845f;   // 1/sqrt(128)
constexpr float LOG2E = 1.4426950408889634f;
constexpr float LOG2_127 = 6.988684686772166f;

// ---- workspace layout (bytes) ----
constexpr size_t OFF_WSUM = 0;                                   // double[4]
constexpr size_t OFF_SW   = 64;                                  // float[4]
constexpr size_t OFF_WT   = 256;                                 // int8[4][C*C] ternary
constexpr size_t OFF_XQ   = OFF_WT   + (size_t)4 * C_ * C_;      // int8[R*C]
constexpr size_t OFF_SX   = OFF_XQ   + (size_t)R_ * C_;          // float[R]
constexpr size_t OFF_QKV  = OFF_SX   + (size_t)R_ * 4;           // int8[3][B*H*T*D]
constexpr size_t OFF_SQKV = OFF_QKV  + (size_t)3 * R_ * C_;      // float[3][B*H*T]
constexpr size_t OFF_YQ   = OFF_SQKV + (size_t)3 * R_ * H_ * 4;  // int8[R*C]
constexpr size_t OFF_SY   = OFF_YQ   + (size_t)R_ * C_;          // float[R*H]
constexpr size_t OFF_OUTP = OFF_SY   + (size_t)R_ * H_ * 4;      // float[R*C]
// vT (bf16 hi/lo interleaved PV-fragment layout, 33.55 MB) aliases OUTP (33.55 MB):
// dead before outproj writes outp (stream-ordered), so no extra workspace.
constexpr size_t OFF_VT   = OFF_OUTP;

typedef int   i32x4 __attribute__((ext_vector_type(4)));
typedef short s16x8 __attribute__((ext_vector_type(8)));
typedef float f32x4 __attribute__((ext_vector_type(4)));
typedef unsigned int u32x4 __attribute__((ext_vector_type(4)));

__device__ __forceinline__ i32x4 mfma_i8(i32x4 a, i32x4 b, i32x4 c) {
  return __builtin_amdgcn_mfma_i32_16x16x64_i8(a, b, c, 0, 0, 0);
}
__device__ __forceinline__ f32x4 mfma_bf16(s16x8 a, s16x8 b, f32x4 c) {
  return __builtin_amdgcn_mfma_f32_16x16x32_bf16(a, b, c, 0, 0, 0);
}

// async global->LDS DMA, 16B per lane; LDS dest = wave-uniform base + lane*16
__device__ __forceinline__ void dma16(const void* g, void* l) {
  __builtin_amdgcn_global_load_lds(
      (const __attribute__((address_space(1))) void*)g,
      (__attribute__((address_space(3))) void*)l, 16, 0, 0);
}

#if __has_builtin(__builtin_amdgcn_exp2f)
__device__ __forceinline__ float fast_exp2(float x) { return __builtin_amdgcn_exp2f(x); }
#else
__device__ __forceinline__ float fast_exp2(float x) { return exp2f(x); }
#endif

// RTNE float->bf16 bits (matches numpy RTNE)
__device__ __forceinline__ short f2bf(float f) {
  union { float f; uint32_t u; } v; v.f = f;
  uint32_t r = v.u + 0x7fffu + ((v.u >> 16) & 1u);
  return (short)(r >> 16);
}
__device__ __forceinline__ float bf2f(short h) {
  union { uint32_t u; float f; } v; v.u = ((uint32_t)(uint16_t)h) << 16;
  return v.f;
}

// ---------------- mean(|W|) for the 4 weight matrices (double accum) ----------------
__global__ __launch_bounds__(256) void wabs_sum_kernel(
    const float* __restrict__ W0, const float* __restrict__ W1,
    const float* __restrict__ W2, const float* __restrict__ W3,
    double* __restrict__ wsum)
{
  const int w   = blockIdx.x >> 6;
  const int blk = blockIdx.x & 63;
  const float* W = (w == 0) ? W0 : (w == 1) ? W1 : (w == 2) ? W2 : W3;
  const int n = C_ * C_;
  double s = 0.0;
  for (int i = blk * 256 + (int)threadIdx.x; i < n; i += 64 * 256)
    s += (double)fabsf(W[i]);
  __shared__ double sm[256];
  sm[threadIdx.x] = s;
  __syncthreads();
  for (int o = 128; o > 0; o >>= 1) {
    if ((int)threadIdx.x < o) sm[threadIdx.x] += sm[threadIdx.x + o];
    __syncthreads();
  }
  if (threadIdx.x == 0) atomicAdd(&wsum[w], sm[0]);
}

// ---------------- ternary weight quant ----------------
__global__ __launch_bounds__(256) void wquant_kernel(
    const float* __restrict__ W0, const float* __restrict__ W1,
    const float* __restrict__ W2, const float* __restrict__ W3,
    const double* __restrict__ wsum, int8_t* __restrict__ Wt, float* __restrict__ sw)
{
  const int w = blockIdx.x >> 10;
  const float* W = (w == 0) ? W0 : (w == 1) ? W1 : (w == 2) ? W2 : W3;
  const int n = C_ * C_;
  const float s = fmaxf((float)(wsum[w] * (1.0 / (double)n)), EPSF);
  int8_t* dst = Wt + (size_t)w * n;
  const int base = (blockIdx.x & 1023) * 256 + (int)threadIdx.x;
  for (int i = base; i < n; i += 1024 * 256) {
    float t = rintf(W[i] / s);
    t = fminf(fmaxf(t, -1.f), 1.f);
    dst[i] = (int8_t)t;
  }
  if (base == 0) sw[w] = s;
}

// ---------------- per-token act_quant of x ----------------
__global__ __launch_bounds__(256) void xquant_kernel(
    const float* __restrict__ x, int8_t* __restrict__ xq, float* __restrict__ sx)
{
  const int r = blockIdx.x;
  const float* xr = x + (size_t)r * C_;
  float am = 0.f;
  for (int j = threadIdx.x; j < C_; j += 256) am = fmaxf(am, fabsf(xr[j]));
  __shared__ float sm[256];
  sm[threadIdx.x] = am;
  __syncthreads();
  for (int o = 128; o > 0; o >>= 1) {
    if ((int)threadIdx.x < o) sm[threadIdx.x] = fmaxf(sm[threadIdx.x], sm[threadIdx.x + o]);
    __syncthreads();
  }
  const float m = fmaxf(sm[0], EPSF);
  const float scale = 127.f / m;
  for (int j = threadIdx.x; j < C_; j += 256) {
    float q = fminf(fmaxf(rintf(xr[j] * scale), -128.f), 127.f);
    xq[(size_t)r * C_ + j] = (int8_t)q;
  }
  if (threadIdx.x == 0) sx[r] = m / 127.f;
}

// ---------------- q/k/v projection v3: counted-vmcnt at UNCHANGED occupancy ---------
// R7 post-mortem: 3-buffer transplant grew LDS 32.5->48.5KB, occupancy 4->3 blocks/CU,
// total +14us (cross-block overlap matters more than intra-block pipelining here).
// v3: 2 buffers (LDS 32.5KB, 4 blocks/CU preserved) + counted vmcnt. The WAR race
// (stage into buffer a slow wave still reads) is closed by a SECOND raw s_barrier
// after compute — no vmcnt(0) drain anywhere. stage(kc+1) now issues BEFORE the wait
// for chunk kc -> a full extra iteration of DMA flight time (the attn v13 mechanism).
__global__ __launch_bounds__(256) void proj_mfma_kernel(
    const int8_t* __restrict__ xq, const float* __restrict__ sx,
    const int8_t* __restrict__ Wt, const float* __restrict__ sw4,
    int8_t* __restrict__ qkv, float* __restrict__ sqkv)
{
  const int h    = blockIdx.x;
  const int r0   = blockIdx.y * 128;
  const int wsel = blockIdx.z;
  const int tid  = (int)threadIdx.x;
  const int wv   = tid >> 6;
  const int lane = tid & 63;
  const int quad = lane >> 4;
  const int l15  = lane & 15;
  const int rh   = wv >> 1, ch = wv & 1;
  const int8_t* Wm = Wt + (size_t)wsel * C_ * C_;

  __shared__ __align__(16) char As[2][8192];   // 512 slots x 16B, swizzled
  __shared__ __align__(16) char Bs[2][8192];
  __shared__ int rmaxs[128];
  if (tid < 128) rmaxs[tid] = 0;

  const int s0a   = wv * 128;
  const int rowA0 = (s0a + lane) >> 2;
  const int qdA0  = ((s0a + lane) & 3) ^ (rowA0 & 3);
  const int rowA1 = (s0a + 64 + lane) >> 2;
  const int qdA1  = ((s0a + 64 + lane) & 3) ^ (rowA1 & 3);

  auto stage = [&](int bf, int k0) {
    dma16(xq + (size_t)(r0 + rowA0) * C_ + k0 + qdA0 * 16, &As[bf][(s0a) * 16]);
    dma16(xq + (size_t)(r0 + rowA1) * C_ + k0 + qdA1 * 16, &As[bf][(s0a + 64) * 16]);
    dma16(Wm + (size_t)(h * 128 + rowA0) * C_ + k0 + qdA0 * 16, &Bs[bf][(s0a) * 16]);
    dma16(Wm + (size_t)(h * 128 + rowA1) * C_ + k0 + qdA1 * 16, &Bs[bf][(s0a + 64) * 16]);
  };

  i32x4 acc[4][4];
  #pragma unroll
  for (int i = 0; i < 4; ++i)
    #pragma unroll
    for (int j = 0; j < 4; ++j) acc[i][j] = i32x4{0, 0, 0, 0};

  stage(0, 0);
  for (int kc = 0; kc < 32; ++kc) {
    if (kc + 1 < 32) {
      stage((kc + 1) & 1, (kc + 1) * 64);                // into OTHER buffer
      asm volatile("s_waitcnt vmcnt(4)" ::: "memory");   // chunk-kc's 4 DMAs landed
    } else {
      asm volatile("s_waitcnt vmcnt(0)" ::: "memory");
    }
    __builtin_amdgcn_s_barrier();                        // all waves: chunk kc ready
    asm volatile("" ::: "memory");

    const char* Ab = As[kc & 1];
    const char* Bb = Bs[kc & 1];
    i32x4 a[4], b[4];
    #pragma unroll
    for (int rt = 0; rt < 4; ++rt) {
      const int row = rh * 64 + rt * 16 + l15;
      a[rt] = *(const i32x4*)(Ab + (row * 4 + (quad ^ (row & 3))) * 16);
    }
    #pragma unroll
    for (int ct = 0; ct < 4; ++ct) {
      const int col = ch * 64 + ct * 16 + l15;
      b[ct] = *(const i32x4*)(Bb + (col * 4 + (quad ^ (col & 3))) * 16);
    }
    #pragma unroll
    for (int rt = 0; rt < 4; ++rt)
      #pragma unroll
      for (int ct = 0; ct < 4; ++ct)
        acc[rt][ct] = mfma_i8(a[rt], b[ct], acc[rt][ct]);

    __builtin_amdgcn_s_barrier();                        // reads of buf kc&1 done:
    asm volatile("" ::: "memory");                       // safe to stage kc+2 into it
  }

  #pragma unroll
  for (int rt = 0; rt < 4; ++rt)
    #pragma unroll
    for (int r = 0; r < 4; ++r) {
      int m = 0;
      #pragma unroll
      for (int ct = 0; ct < 4; ++ct) {
        int v = acc[rt][ct][r];
        int av = v < 0 ? -v : v;
        m = m > av ? m : av;
      }
      #pragma unroll
      for (int mm = 1; mm < 16; mm <<= 1) {
        int o = __shfl_xor(m, mm, 64);
        m = m > o ? m : o;
      }
      if (l15 == 0) atomicMax(&rmaxs[rh * 64 + rt * 16 + quad * 4 + r], m);
    }
  __syncthreads();

  const float swv = sw4[wsel];
  #pragma unroll
  for (int rt = 0; rt < 4; ++rt)
    #pragma unroll
    for (int r = 0; r < 4; ++r) {
      const int rowl = rh * 64 + rt * 16 + quad * 4 + r;
      const int rglob = r0 + rowl;
      const int mN = rmaxs[rowl];
      const float qscale = (mN > 0) ? 127.f / (float)mN : 0.f;
      const int bb = rglob >> 11;
      const int tt = rglob & (T_ - 1);
      const size_t obase = ((size_t)(bb * H_ + h) * T_ + tt) * D_;
      #pragma unroll
      for (int ct = 0; ct < 4; ++ct) {
        const int col = ch * 64 + ct * 16 + l15;
        float q = rintf((float)acc[rt][ct][r] * qscale);
        q = fminf(fmaxf(q, -128.f), 127.f);
        qkv[(size_t)wsel * R_ * C_ + obase + col] = (int8_t)q;
      }
      if (ch == 0 && l15 == 0) {
        float maxq = (float)mN * sx[rglob] * swv;
        sqkv[(size_t)wsel * R_ * H_ + (size_t)(bb * H_ + h) * T_ + tt] =
            fmaxf(maxq, EPSF) / 127.f;
      }
    }
}

// ---------------- V dequant+transpose: int8 [bh][t][d] -> PV-fragment layout ---------
// Output vT: per (bh, d, 32-key chunk c) one 128B row of 8 x 16B segs.
//   seg ((2g + d) & 7)     = hi bf16 of keys { kt*16 + g*4 + r : kt in 0..1, r in 0..3 }
//   seg ((2g + 1 + d) & 7) = lo bf16 of the same keys
// Rotation by d makes every wave64 ds_read_b128 conflict-free (each consecutive
// 8-lane group hits 8 distinct 16B slots). Unchanged from v11/v12 (verified).
__global__ __launch_bounds__(256) void vtrans_kernel(
    const int8_t* __restrict__ vq, const float* __restrict__ sv,
    short* __restrict__ vT)
{
  const int bh = blockIdx.y;
  const int s0 = blockIdx.x * 64;
  const int tid = (int)threadIdx.x;
  __shared__ __align__(16) int8_t Vs[64][144];
  __shared__ float svs[64];
  const int8_t* vbase = vq + ((size_t)bh * T_ + s0) * D_;
  #pragma unroll
  for (int it = 0; it < 2; ++it) {
    int idx = tid + it * 256;
    int row = idx >> 3, seg = idx & 7;
    *(uint4*)(&Vs[row][seg * 16]) = *(const uint4*)(vbase + row * 128 + seg * 16);
  }
  if (tid < 64) svs[tid] = sv[(size_t)bh * T_ + s0 + tid];
  __syncthreads();
  const int d    = tid >> 1;
  const int half = tid & 1;            // which 32-key chunk within this block
  const int kh   = half * 32;
  uint32_t oh[16], ol[16];
  #pragma unroll
  for (int i = 0; i < 32; i += 2) {
    const int k0 = kh + i, k1 = kh + i + 1;
    float v0 = (float)(int)Vs[k0][d] * svs[k0];
    float v1 = (float)(int)Vs[k1][d] * svs[k1];
    short h0 = f2bf(v0), h1 = f2bf(v1);
    short l0 = f2bf(v0 - bf2f(h0)), l1 = f2bf(v1 - bf2f(h1));
    oh[i >> 1] = (uint32_t)(uint16_t)h0 | ((uint32_t)(uint16_t)h1 << 16);
    ol[i >> 1] = (uint32_t)(uint16_t)l0 | ((uint32_t)(uint16_t)l1 << 16);
  }
  const int c = (s0 >> 5) + half;      // global 32-key chunk index (0..63)
  char* out = (char*)vT + ((((size_t)bh * 128 + d) * 64 + (size_t)c) << 7);
  const int par = d & 7;
  #pragma unroll
  for (int g = 0; g < 4; ++g) {
    uint4 hi, lo;
    hi.x = oh[2 * g];     hi.y = oh[2 * g + 1];
    hi.z = oh[2 * g + 8]; hi.w = oh[2 * g + 9];
    lo.x = ol[2 * g];     lo.y = ol[2 * g + 1];
    lo.z = ol[2 * g + 8]; lo.w = ol[2 * g + 9];
    *(uint4*)(out + (((2 * g + par) & 7) << 4))     = hi;
    *(uint4*)(out + (((2 * g + 1 + par) & 7) << 4)) = lo;
  }
}

// ---------------- fused attention v13: counted-vmcnt pipeline (T3/T4) ----------------
// UNCHANGED from measured-best (153.7-155.0us, Mfma 28.6 / VALU 37.2). See R5 notes.
__global__ __launch_bounds__(256, 2) void attn_mfma_kernel(
    const int8_t* __restrict__ qq, const int8_t* __restrict__ kq,
    const float* __restrict__ sq, const float* __restrict__ sk,
    const short* __restrict__ vT,
    int8_t* __restrict__ yq, float* __restrict__ sy)
{
  const int bh  = blockIdx.x;
  const int t0  = blockIdx.y * 128;
  const int tid = (int)threadIdx.x;
  const int w    = tid >> 6;           // 4 waves
  const int lane = tid & 63;
  const int quad = lane >> 4;
  const int l15  = lane & 15;

  // LDS: K bufs 3x4KB [0,12288); V bufs 3x16KB [12288,61440); sks [61440,69632)
  __shared__ __align__(16) char smem[69632];
  float* sks = (float*)(smem + 61440);

  const int qrow0 = t0 + 32 * w;

  const int8_t* kq_bh = kq + (size_t)bh * T_ * D_;
  const char*   vb    = (const char*)vT + ((size_t)bh << 20);

  const int kslot = w * 64 + lane;               // 0..255
  const int kkey  = kslot >> 3;                  // 0..31
  const int ksrc  = ((kslot & 7) ^ (kkey & 7)) * 16;
  auto stageK = [&](int buf, int cc) {
    dma16(kq_bh + (size_t)(cc * 32 + kkey) * 128 + ksrc,
          smem + buf * 4096 + (w * 64) * 16);
  };

  const size_t vlane = (size_t)(w * 32 + (lane >> 3)) * 8192 + (size_t)((lane & 7) * 16);
  auto stageV = [&](int buf, int cc) {
    char* dst = smem + 12288 + buf * 16384 + (w * 32) * 128;
    const char* src = vb + vlane + (size_t)cc * 128;
    #pragma unroll
    for (int j = 0; j < 4; ++j)
      dma16(src + (size_t)(j * 8) * 8192, dst + j * 1024);
  };

  {
    const float* skg = sk + (size_t)bh * T_;
    dma16(skg + (w * 2 + 0) * 256 + lane * 4, smem + 61440 + (w * 2 + 0) * 1024);
    dma16(skg + (w * 2 + 1) * 256 + lane * 4, smem + 61440 + (w * 2 + 1) * 1024);
  }
  stageK(0, 0);
  stageV(0, 0);

  i32x4 qf[2][2];
  #pragma unroll
  for (int qt = 0; qt < 2; ++qt)
    #pragma unroll
    for (int hf = 0; hf < 2; ++hf)
      qf[qt][hf] = *(const i32x4*)(qq + ((size_t)bh * T_ + qrow0 + qt * 16 + l15) * D_ +
                                   hf * 64 + quad * 16);
  float f0[2];
  #pragma unroll
  for (int qt = 0; qt < 2; ++qt)
    f0[qt] = sq[(size_t)bh * T_ + qrow0 + qt * 16 + l15] * INV_SQRT_D;

  __syncthreads();   // sks + chunk-0 visible before pass 1

  const int8_t* kqb = kq_bh + (size_t)(l15 * D_ + quad * 16);

  // ---- pass 1: exact rowmax of c*sk; global K stream, sk from LDS, no barriers ----
  float rx[2][4];
  #pragma unroll
  for (int qt = 0; qt < 2; ++qt)
    #pragma unroll
    for (int r = 0; r < 4; ++r) rx[qt][r] = -3e38f;

  for (int s0 = 0; s0 < T_; s0 += 64) {
    #pragma unroll
    for (int kt = 0; kt < 4; ++kt) {
      const f32x4 skv = *(const f32x4*)(sks + s0 + kt * 16 + quad * 4);
      const i32x4 ka = *(const i32x4*)(kqb + (size_t)(s0 + kt * 16) * D_);
      const i32x4 kb = *(const i32x4*)(kqb + (size_t)(s0 + kt * 16) * D_ + 64);
      #pragma unroll
      for (int qt = 0; qt < 2; ++qt) {
        i32x4 c = i32x4{0, 0, 0, 0};
        c = mfma_i8(ka, qf[qt][0], c);
        c = mfma_i8(kb, qf[qt][1], c);
        #pragma unroll
        for (int r = 0; r < 4; ++r)
          rx[qt][r] = fmaxf(rx[qt][r], (float)c[r] * skv[r]);
      }
    }
  }
  float f1[2], g[2];
  #pragma unroll
  for (int qt = 0; qt < 2; ++qt) {
    float m = fmaxf(fmaxf(rx[qt][0], rx[qt][1]), fmaxf(rx[qt][2], rx[qt][3]));
    m = fmaxf(m, __shfl_xor(m, 16, 64));
    m = fmaxf(m, __shfl_xor(m, 32, 64));
    f1[qt] = f0[qt] * LOG2E;
    g[qt]  = LOG2_127 - (m * f0[qt]) * LOG2E;
  }

  // ---- pass 2: quantized softmax (in-register weights) + PV, 64 x 32-key chunks ----
  float zac[2][4] = {};
  f32x4 yacc[2][8];
  #pragma unroll
  for (int qt = 0; qt < 2; ++qt)
    #pragma unroll
    for (int dt = 0; dt < 8; ++dt) yacc[qt][dt] = f32x4{0.f, 0.f, 0.f, 0.f};

  const int seg_hi = ((2 * quad + l15) & 7) << 4;
  const int seg_lo = ((2 * quad + 1 + l15) & 7) << 4;

  int bc = 0, bn = 1;
  for (int c = 0; c < 64; ++c) {
    const int s0k = c * 32;
    if (c + 1 < 64) {
      stageK(bn, c + 1);
      stageV(bn, c + 1);
      asm volatile("s_waitcnt vmcnt(5)" ::: "memory");   // own chunk-c DMAs done
    } else {
      asm volatile("s_waitcnt vmcnt(0)" ::: "memory");
    }
    __builtin_amdgcn_s_barrier();                        // all waves' chunk-c done
    asm volatile("" ::: "memory");                       // pin reads after barrier

    const char* Kb = smem + bc * 4096;
    uint32_t wdw[2][2][2];
    #pragma unroll
    for (int kt = 0; kt < 2; ++kt) {
      const f32x4 skv = *(const f32x4*)(sks + s0k + kt * 16 + quad * 4);
      const int key = kt * 16 + l15;
      const i32x4 ka = *(const i32x4*)(Kb + key * 128 + ((quad ^ (key & 7)) << 4));
      const i32x4 kb = *(const i32x4*)(Kb + key * 128 + (((quad + 4) ^ (key & 7)) << 4));
      #pragma unroll
      for (int qt = 0; qt < 2; ++qt) {
        i32x4 cc = i32x4{0, 0, 0, 0};
        cc = mfma_i8(ka, qf[qt][0], cc);
        cc = mfma_i8(kb, qf[qt][1], cc);
        float wq_[4];
        #pragma unroll
        for (int r = 0; r < 4; ++r) {
          float t = (float)cc[r] * skv[r];
          float wu = fast_exp2(fmaf(t, f1[qt], g[qt]));  // = 127*exp(s-m)
          zac[qt][r] += wu;
          wq_[r] = rintf(wu);                            // integer in [0,127]
        }
        wdw[qt][kt][0] = (__float_as_uint(wq_[0]) >> 16) |
                         (__float_as_uint(wq_[1]) & 0xffff0000u);
        wdw[qt][kt][1] = (__float_as_uint(wq_[2]) >> 16) |
                         (__float_as_uint(wq_[3]) & 0xffff0000u);
      }
    }

    s16x8 wf[2];
    #pragma unroll
    for (int qt = 0; qt < 2; ++qt) {
      u32x4 tw;
      tw[0] = wdw[qt][0][0]; tw[1] = wdw[qt][0][1];
      tw[2] = wdw[qt][1][0]; tw[3] = wdw[qt][1][1];
      wf[qt] = __builtin_bit_cast(s16x8, tw);
    }

    const char* Vc = smem + 12288 + bc * 16384;
    __builtin_amdgcn_s_setprio(1);
    #pragma unroll
    for (int dt = 0; dt < 8; ++dt) {
      const char* rowp = Vc + (dt * 16 + l15) * 128;
      const s16x8 vh = *(const s16x8*)(rowp + seg_hi);
      const s16x8 vl = *(const s16x8*)(rowp + seg_lo);
      yacc[0][dt] = mfma_bf16(wf[0], vh, yacc[0][dt]);
      yacc[0][dt] = mfma_bf16(wf[0], vl, yacc[0][dt]);
      yacc[1][dt] = mfma_bf16(wf[1], vh, yacc[1][dt]);
      yacc[1][dt] = mfma_bf16(wf[1], vl, yacc[1][dt]);
    }
    __builtin_amdgcn_s_setprio(0);

    bc = bn; bn = (bn == 2) ? 0 : bn + 1;
  }

  // ---- epilogue: z reduce over quads, transpose to yacc's row layout, quantize ----
  float zq[2];
  #pragma unroll
  for (int qt = 0; qt < 2; ++qt) {
    float z = (zac[qt][0] + zac[qt][1]) + (zac[qt][2] + zac[qt][3]);
    z += __shfl_xor(z, 16, 64);
    z += __shfl_xor(z, 32, 64);
    zq[qt] = z;                       // all lanes: 127*Z for q = l15
  }

  const int b = bh >> 4;
  const int h = bh & 15;
  #pragma unroll
  for (int qt = 0; qt < 2; ++qt)
    #pragma unroll
    for (int r = 0; r < 4; ++r) {
      const float zr = __shfl(zq[qt], quad * 4 + r, 64);   // z for q = quad*4+r
      float ym = 0.f;
      #pragma unroll
      for (int dt = 0; dt < 8; ++dt) ym = fmaxf(ym, fabsf(yacc[qt][dt][r]));
      #pragma unroll
      for (int mm = 1; mm < 16; mm <<= 1) ym = fmaxf(ym, __shfl_xor(ym, mm, 64));
      const float invz = 1.f / zr;
      const float ymt = fmaxf(ym * invz, EPSF);
      const float fs = 127.f / ymt;
      const int tglob = t0 + 32 * w + qt * 16 + quad * 4 + r;
      const size_t rowbase = ((size_t)(b * T_ + tglob)) * C_ + h * D_;
      #pragma unroll
      for (int dt = 0; dt < 8; ++dt) {
        float yv = yacc[qt][dt][r] * invz;
        float qv = fminf(fmaxf(rintf(yv * fs), -128.f), 127.f);
        yq[rowbase + dt * 16 + l15] = (int8_t)qv;
      }
      if (l15 == 0)
        sy[(size_t)(b * T_ + tglob) * H_ + h] = ymt / 127.f;
    }
}

// ---------------- output projection v4: counted-vmcnt at UNCHANGED occupancy --------
// Same scheme as proj v3: 2 buffers (LDS 32KB), stage -> vmcnt(3) -> barrier ->
// compute -> barrier. Math byte-identical.
__global__ __launch_bounds__(256) void outproj_mfma_kernel(
    const int8_t* __restrict__ yq, const float* __restrict__ sy,
    const int8_t* __restrict__ Wt, const float* __restrict__ sw4,
    float* __restrict__ outp)
{
  const int n0  = blockIdx.x * 64;
  const int r0  = blockIdx.y * 128;
  const int tid = (int)threadIdx.x;
  const int wv   = tid >> 6;
  const int lane = tid & 63;
  const int quad = lane >> 4;
  const int l15  = lane & 15;
  const int rh   = wv >> 1, ch = wv & 1;
  const int8_t* Wm = Wt + (size_t)3 * C_ * C_;

  __shared__ __align__(16) char As[2][8192];   // 512 slots x 16B, swizzled
  __shared__ __align__(16) char Bs[2][4096];   // 256 slots x 16B, swizzled
  __shared__ float sYs[128][16];
  for (int idx = tid; idx < 128 * 16; idx += 256)
    sYs[idx >> 4][idx & 15] = sy[(size_t)(r0 + (idx >> 4)) * H_ + (idx & 15)];

  const int s0a   = wv * 128;
  const int rowA0 = (s0a + lane) >> 2;
  const int qdA0  = ((s0a + lane) & 3) ^ (rowA0 & 3);
  const int rowA1 = (s0a + 64 + lane) >> 2;
  const int qdA1  = ((s0a + 64 + lane) & 3) ^ (rowA1 & 3);
  const int sb    = wv * 64 + lane;
  const int colB  = sb >> 2;
  const int qdB   = (sb & 3) ^ (colB & 3);

  auto stage = [&](int bf, int k0) {
    dma16(yq + (size_t)(r0 + rowA0) * C_ + k0 + qdA0 * 16, &As[bf][(s0a) * 16]);
    dma16(yq + (size_t)(r0 + rowA1) * C_ + k0 + qdA1 * 16, &As[bf][(s0a + 64) * 16]);
    dma16(Wm + (size_t)(n0 + colB) * C_ + k0 + qdB * 16, &Bs[bf][(wv * 64) * 16]);
  };

  i32x4 iacc[4][2];
  f32x4 facc[4][2];
  #pragma unroll
  for (int i = 0; i < 4; ++i)
    #pragma unroll
    for (int j = 0; j < 2; ++j) { iacc[i][j] = i32x4{0,0,0,0}; facc[i][j] = f32x4{0.f,0.f,0.f,0.f}; }

  stage(0, 0);
  for (int kc = 0; kc < 32; ++kc) {
    if (kc + 1 < 32) {
      stage((kc + 1) & 1, (kc + 1) * 64);
      asm volatile("s_waitcnt vmcnt(3)" ::: "memory");   // chunk-kc DMAs landed
    } else {
      asm volatile("s_waitcnt vmcnt(0)" ::: "memory");
    }
    __builtin_amdgcn_s_barrier();
    asm volatile("" ::: "memory");

    const char* Ab = As[kc & 1];
    const char* Bb = Bs[kc & 1];
    i32x4 a[4], b[2];
    #pragma unroll
    for (int rt = 0; rt < 4; ++rt) {
      const int row = rh * 64 + rt * 16 + l15;
      a[rt] = *(const i32x4*)(Ab + (row * 4 + (quad ^ (row & 3))) * 16);
    }
    #pragma unroll
    for (int ct = 0; ct < 2; ++ct) {
      const int col = ch * 32 + ct * 16 + l15;
      b[ct] = *(const i32x4*)(Bb + (col * 4 + (quad ^ (col & 3))) * 16);
    }
    #pragma unroll
    for (int rt = 0; rt < 4; ++rt)
      #pragma unroll
      for (int ct = 0; ct < 2; ++ct)
        iacc[rt][ct] = mfma_i8(a[rt], b[ct], iacc[rt][ct]);
    if (kc & 1) {
      const int hd = kc >> 1;
      #pragma unroll
      for (int rt = 0; rt < 4; ++rt)
        #pragma unroll
        for (int r = 0; r < 4; ++r) {
          const float s = sYs[rh * 64 + rt * 16 + quad * 4 + r][hd];
          #pragma unroll
          for (int ct = 0; ct < 2; ++ct)
            facc[rt][ct][r] += (float)iacc[rt][ct][r] * s;
        }
      #pragma unroll
      for (int rt = 0; rt < 4; ++rt)
        #pragma unroll
        for (int ct = 0; ct < 2; ++ct) iacc[rt][ct] = i32x4{0,0,0,0};
    }

    __builtin_amdgcn_s_barrier();                        // reads of buf kc&1 done
    asm volatile("" ::: "memory");
  }
  const float swp = sw4[3];
  #pragma unroll
  for (int rt = 0; rt < 4; ++rt)
    #pragma unroll
    for (int r = 0; r < 4; ++r) {
      const int rowl = rh * 64 + rt * 16 + quad * 4 + r;
      #pragma unroll
      for (int ct = 0; ct < 2; ++ct)
        outp[(size_t)(r0 + rowl) * C_ + n0 + ch * 32 + ct * 16 + l15] =
            facc[rt][ct][r] * swp;
    }
}

// ---------------- final per-token act_quant ----------------
__global__ __launch_bounds__(256) void final_quant_kernel(
    const float* __restrict__ outp, float* __restrict__ out)
{
  const int r = blockIdx.x;
  const float* xr = outp + (size_t)r * C_;
  float am = 0.f;
  for (int j = threadIdx.x; j < C_; j += 256) am = fmaxf(am, fabsf(xr[j]));
  __shared__ float sm[256];
  sm[threadIdx.x] = am;
  __syncthreads();
  for (int o = 128; o > 0; o >>= 1) {
    if ((int)threadIdx.x < o) sm[threadIdx.x] = fmaxf(sm[threadIdx.x], sm[threadIdx.x + o]);
    __syncthreads();
  }
  const float m = fmaxf(sm[0], EPSF);
  const float scale = 127.f / m;
  const float inv = m / 127.f;
  for (int j = threadIdx.x; j < C_; j += 256) {
    float q = fminf(fmaxf(rintf(xr[j] * scale), -128.f), 127.f);
    out[(size_t)r * C_ + j] = q * inv;
  }
}

} // namespace

extern "C" void kernel_launch(void* const* d_in, const int* in_sizes, int n_in,
                              void* d_out, int out_size, void* d_ws, size_t ws_size,
                              hipStream_t stream)
{
  (void)in_sizes; (void)n_in; (void)out_size; (void)ws_size;
  const float* x  = (const float*)d_in[0];
  const float* W0 = (const float*)d_in[1];
  const float* W1 = (const float*)d_in[2];
  const float* W2 = (const float*)d_in[3];
  const float* W3 = (const float*)d_in[4];

  char* ws = (char*)d_ws;
  double* wsum = (double*)(ws + OFF_WSUM);
  float*  swv  = (float*) (ws + OFF_SW);
  int8_t* Wt   = (int8_t*)(ws + OFF_WT);
  int8_t* xq   = (int8_t*)(ws + OFF_XQ);
  float*  sx   = (float*) (ws + OFF_SX);
  int8_t* qkv  = (int8_t*)(ws + OFF_QKV);
  float*  sqkv = (float*) (ws + OFF_SQKV);
  int8_t* yqp  = (int8_t*)(ws + OFF_YQ);
  float*  syp  = (float*) (ws + OFF_SY);
  float*  outp = (float*) (ws + OFF_OUTP);
  short*  vT   = (short*) (ws + OFF_VT);           // aliases outp

  hipMemsetAsync(d_ws, 0, 256, stream);
  hipLaunchKernelGGL(wabs_sum_kernel, dim3(256), dim3(256), 0, stream, W0, W1, W2, W3, wsum);
  hipLaunchKernelGGL(wquant_kernel, dim3(4096), dim3(256), 0, stream, W0, W1, W2, W3, wsum, Wt, swv);
  hipLaunchKernelGGL(xquant_kernel, dim3(R_), dim3(256), 0, stream, x, xq, sx);
  hipLaunchKernelGGL(proj_mfma_kernel, dim3(H_, R_ / 128, 3), dim3(256), 0, stream,
                     xq, sx, Wt, swv, qkv, sqkv);
  hipLaunchKernelGGL(vtrans_kernel, dim3(T_ / 64, B_ * H_), dim3(256), 0, stream,
                     qkv + (size_t)2 * R_ * C_, sqkv + (size_t)2 * R_ * H_, vT);
  hipLaunchKernelGGL(attn_mfma_kernel, dim3(B_ * H_, T_ / 128), dim3(256), 0, stream,
                     qkv, qkv + (size_t)R_ * C_,
                     sqkv, sqkv + (size_t)R_ * H_,
                     vT, yqp, syp);
  hipLaunchKernelGGL(outproj_mfma_kernel, dim3(C_ / 64, R_ / 128), dim3(256), 0, stream,
                     yqp, syp, Wt, swv, outp);
  hipLaunchKernelGGL(final_quant_kernel, dim3(R_), dim3(256), 0, stream, outp, (float*)d_out);
}

// Round 9
// 446.428 us; speedup vs baseline: 1.2157x; 1.2039x over previous
//
#include <hip/hip_runtime.h>
#include <stdint.h>

namespace {

constexpr int B_ = 2, T_ = 2048, C_ = 2048, H_ = 16, D_ = 128;
constexpr int R_ = B_ * T_;                 // 4096 token rows (b*T + t)
constexpr float EPSF = 1e-5f;
constexpr float INV_SQRT_D = 0.08838834764831845f;   // 1/sqrt(128)
constexpr float LOG2E = 1.4426950408889634f;
constexpr float LOG2_127 = 6.988684686772166f;

// ---- workspace layout (bytes) ----
constexpr size_t OFF_WSUM = 0;                                   // double[4]
constexpr size_t OFF_SW   = 64;                                  // float[4]
constexpr size_t OFF_WT   = 256;                                 // int8[4][C*C] ternary
constexpr size_t OFF_XQ   = OFF_WT   + (size_t)4 * C_ * C_;      // int8[R*C]
constexpr size_t OFF_SX   = OFF_XQ   + (size_t)R_ * C_;          // float[R]
constexpr size_t OFF_QKV  = OFF_SX   + (size_t)R_ * 4;           // int8[3][B*H*T*D]
constexpr size_t OFF_SQKV = OFF_QKV  + (size_t)3 * R_ * C_;      // float[3][B*H*T]
constexpr size_t OFF_YQ   = OFF_SQKV + (size_t)3 * R_ * H_ * 4;  // int8[R*C]
constexpr size_t OFF_SY   = OFF_YQ   + (size_t)R_ * C_;          // float[R*H]
constexpr size_t OFF_OUTP = OFF_SY   + (size_t)R_ * H_ * 4;      // float[R*C]
// vT (bf16 hi/lo interleaved PV-fragment layout, 33.55 MB) aliases OUTP (33.55 MB):
// dead before outproj writes outp (stream-ordered), so no extra workspace.
constexpr size_t OFF_VT   = OFF_OUTP;

typedef int   i32x4 __attribute__((ext_vector_type(4)));
typedef short s16x8 __attribute__((ext_vector_type(8)));
typedef float f32x4 __attribute__((ext_vector_type(4)));
typedef unsigned int u32x4 __attribute__((ext_vector_type(4)));

__device__ __forceinline__ i32x4 mfma_i8(i32x4 a, i32x4 b, i32x4 c) {
  return __builtin_amdgcn_mfma_i32_16x16x64_i8(a, b, c, 0, 0, 0);
}
__device__ __forceinline__ f32x4 mfma_bf16(s16x8 a, s16x8 b, f32x4 c) {
  return __builtin_amdgcn_mfma_f32_16x16x32_bf16(a, b, c, 0, 0, 0);
}

// async global->LDS DMA, 16B per lane; LDS dest = wave-uniform base + lane*16
__device__ __forceinline__ void dma16(const void* g, void* l) {
  __builtin_amdgcn_global_load_lds(
      (const __attribute__((address_space(1))) void*)g,
      (__attribute__((address_space(3))) void*)l, 16, 0, 0);
}

#if __has_builtin(__builtin_amdgcn_exp2f)
__device__ __forceinline__ float fast_exp2(float x) { return __builtin_amdgcn_exp2f(x); }
#else
__device__ __forceinline__ float fast_exp2(float x) { return exp2f(x); }
#endif

// RTNE float->bf16 bits (matches numpy RTNE)
__device__ __forceinline__ short f2bf(float f) {
  union { float f; uint32_t u; } v; v.f = f;
  uint32_t r = v.u + 0x7fffu + ((v.u >> 16) & 1u);
  return (short)(r >> 16);
}
__device__ __forceinline__ float bf2f(short h) {
  union { uint32_t u; float f; } v; v.u = ((uint32_t)(uint16_t)h) << 16;
  return v.f;
}

// ---------------- mean(|W|): float4-vectorized (G13), double accum ------------------
__global__ __launch_bounds__(256) void wabs_sum_kernel(
    const float* __restrict__ W0, const float* __restrict__ W1,
    const float* __restrict__ W2, const float* __restrict__ W3,
    double* __restrict__ wsum)
{
  const int w   = blockIdx.x >> 6;
  const int blk = blockIdx.x & 63;
  const float* W = (w == 0) ? W0 : (w == 1) ? W1 : (w == 2) ? W2 : W3;
  const float4* W4 = (const float4*)W;
  const int n4 = (C_ * C_) / 4;
  double s = 0.0;
  for (int i = blk * 256 + (int)threadIdx.x; i < n4; i += 64 * 256) {
    float4 v = W4[i];
    s += (double)fabsf(v.x) + (double)fabsf(v.y) +
         (double)fabsf(v.z) + (double)fabsf(v.w);
  }
  __shared__ double sm[256];
  sm[threadIdx.x] = s;
  __syncthreads();
  for (int o = 128; o > 0; o >>= 1) {
    if ((int)threadIdx.x < o) sm[threadIdx.x] += sm[threadIdx.x + o];
    __syncthreads();
  }
  if (threadIdx.x == 0) atomicAdd(&wsum[w], sm[0]);
}

// ---------------- ternary weight quant: float4 load, packed int8x4 store ------------
// Per-element math identical (division kept: rintf(W/s)).
__global__ __launch_bounds__(256) void wquant_kernel(
    const float* __restrict__ W0, const float* __restrict__ W1,
    const float* __restrict__ W2, const float* __restrict__ W3,
    const double* __restrict__ wsum, int8_t* __restrict__ Wt, float* __restrict__ sw)
{
  const int w = blockIdx.x >> 10;
  const float* W = (w == 0) ? W0 : (w == 1) ? W1 : (w == 2) ? W2 : W3;
  const int n = C_ * C_;
  const int n4 = n / 4;
  const float s = fmaxf((float)(wsum[w] * (1.0 / (double)n)), EPSF);
  const float4* W4 = (const float4*)W;
  uint32_t* dst4 = (uint32_t*)(Wt + (size_t)w * n);
  const int base = (blockIdx.x & 1023) * 256 + (int)threadIdx.x;
  for (int i = base; i < n4; i += 1024 * 256) {
    float4 v = W4[i];
    union { int8_t b[4]; uint32_t u; } pk;
    pk.b[0] = (int8_t)fminf(fmaxf(rintf(v.x / s), -1.f), 1.f);
    pk.b[1] = (int8_t)fminf(fmaxf(rintf(v.y / s), -1.f), 1.f);
    pk.b[2] = (int8_t)fminf(fmaxf(rintf(v.z / s), -1.f), 1.f);
    pk.b[3] = (int8_t)fminf(fmaxf(rintf(v.w / s), -1.f), 1.f);
    dst4[i] = pk.u;
  }
  if (base == 0) sw[w] = s;
}

// ---------------- per-token act_quant of x: float4 load, packed int8x4 store --------
__global__ __launch_bounds__(256) void xquant_kernel(
    const float* __restrict__ x, int8_t* __restrict__ xq, float* __restrict__ sx)
{
  const int r = blockIdx.x;
  const float4* xr = (const float4*)(x + (size_t)r * C_);
  float am = 0.f;
  for (int j = threadIdx.x; j < C_ / 4; j += 256) {
    float4 v = xr[j];
    am = fmaxf(am, fmaxf(fmaxf(fabsf(v.x), fabsf(v.y)),
                         fmaxf(fabsf(v.z), fabsf(v.w))));
  }
  __shared__ float sm[256];
  sm[threadIdx.x] = am;
  __syncthreads();
  for (int o = 128; o > 0; o >>= 1) {
    if ((int)threadIdx.x < o) sm[threadIdx.x] = fmaxf(sm[threadIdx.x], sm[threadIdx.x + o]);
    __syncthreads();
  }
  const float m = fmaxf(sm[0], EPSF);
  const float scale = 127.f / m;
  uint32_t* dst4 = (uint32_t*)(xq + (size_t)r * C_);
  for (int j = threadIdx.x; j < C_ / 4; j += 256) {
    float4 v = xr[j];
    union { int8_t b[4]; uint32_t u; } pk;
    pk.b[0] = (int8_t)fminf(fmaxf(rintf(v.x * scale), -128.f), 127.f);
    pk.b[1] = (int8_t)fminf(fmaxf(rintf(v.y * scale), -128.f), 127.f);
    pk.b[2] = (int8_t)fminf(fmaxf(rintf(v.z * scale), -128.f), 127.f);
    pk.b[3] = (int8_t)fminf(fmaxf(rintf(v.w * scale), -128.f), 127.f);
    dst4[j] = pk.u;
  }
  if (threadIdx.x == 0) sx[r] = m / 127.f;
}

// ---------------- q/k/v projection: i8 MFMA, async-DMA double-buffered LDS ----------
// REVERTED to the R6/528.4us form. R7 (3-buf, occupancy 4->3) and R8 (2-buf counted
// vmcnt + double barrier) both measured SLOWER (+14.3/+9.1us): at 4 blocks/CU the
// cross-block overlap already hides the barrier drain; T3/T4 pays only when
// occupancy can't (attn's 2 blocks/CU).
__global__ __launch_bounds__(256) void proj_mfma_kernel(
    const int8_t* __restrict__ xq, const float* __restrict__ sx,
    const int8_t* __restrict__ Wt, const float* __restrict__ sw4,
    int8_t* __restrict__ qkv, float* __restrict__ sqkv)
{
  const int h    = blockIdx.x;
  const int r0   = blockIdx.y * 128;
  const int wsel = blockIdx.z;
  const int tid  = (int)threadIdx.x;
  const int wv   = tid >> 6;
  const int lane = tid & 63;
  const int quad = lane >> 4;
  const int l15  = lane & 15;
  const int rh   = wv >> 1, ch = wv & 1;
  const int8_t* Wm = Wt + (size_t)wsel * C_ * C_;

  __shared__ __align__(16) char As[2][8192];   // 512 slots x 16B, swizzled
  __shared__ __align__(16) char Bs[2][8192];
  __shared__ int rmaxs[128];
  if (tid < 128) rmaxs[tid] = 0;

  const int s0a   = wv * 128;
  const int rowA0 = (s0a + lane) >> 2;
  const int qdA0  = ((s0a + lane) & 3) ^ (rowA0 & 3);
  const int rowA1 = (s0a + 64 + lane) >> 2;
  const int qdA1  = ((s0a + 64 + lane) & 3) ^ (rowA1 & 3);

  auto stage = [&](int bf, int k0) {
    dma16(xq + (size_t)(r0 + rowA0) * C_ + k0 + qdA0 * 16, &As[bf][(s0a) * 16]);
    dma16(xq + (size_t)(r0 + rowA1) * C_ + k0 + qdA1 * 16, &As[bf][(s0a + 64) * 16]);
    dma16(Wm + (size_t)(h * 128 + rowA0) * C_ + k0 + qdA0 * 16, &Bs[bf][(s0a) * 16]);
    dma16(Wm + (size_t)(h * 128 + rowA1) * C_ + k0 + qdA1 * 16, &Bs[bf][(s0a + 64) * 16]);
  };

  i32x4 acc[4][4];
  #pragma unroll
  for (int i = 0; i < 4; ++i)
    #pragma unroll
    for (int j = 0; j < 4; ++j) acc[i][j] = i32x4{0, 0, 0, 0};

  stage(0, 0);
  for (int kc = 0; kc < 32; ++kc) {
    __syncthreads();
    if (kc + 1 < 32) stage((kc + 1) & 1, (kc + 1) * 64);
    const char* Ab = As[kc & 1];
    const char* Bb = Bs[kc & 1];
    i32x4 a[4], b[4];
    #pragma unroll
    for (int rt = 0; rt < 4; ++rt) {
      const int row = rh * 64 + rt * 16 + l15;
      a[rt] = *(const i32x4*)(Ab + (row * 4 + (quad ^ (row & 3))) * 16);
    }
    #pragma unroll
    for (int ct = 0; ct < 4; ++ct) {
      const int col = ch * 64 + ct * 16 + l15;
      b[ct] = *(const i32x4*)(Bb + (col * 4 + (quad ^ (col & 3))) * 16);
    }
    #pragma unroll
    for (int rt = 0; rt < 4; ++rt)
      #pragma unroll
      for (int ct = 0; ct < 4; ++ct)
        acc[rt][ct] = mfma_i8(a[rt], b[ct], acc[rt][ct]);
  }

  #pragma unroll
  for (int rt = 0; rt < 4; ++rt)
    #pragma unroll
    for (int r = 0; r < 4; ++r) {
      int m = 0;
      #pragma unroll
      for (int ct = 0; ct < 4; ++ct) {
        int v = acc[rt][ct][r];
        int av = v < 0 ? -v : v;
        m = m > av ? m : av;
      }
      #pragma unroll
      for (int mm = 1; mm < 16; mm <<= 1) {
        int o = __shfl_xor(m, mm, 64);
        m = m > o ? m : o;
      }
      if (l15 == 0) atomicMax(&rmaxs[rh * 64 + rt * 16 + quad * 4 + r], m);
    }
  __syncthreads();

  const float swv = sw4[wsel];
  #pragma unroll
  for (int rt = 0; rt < 4; ++rt)
    #pragma unroll
    for (int r = 0; r < 4; ++r) {
      const int rowl = rh * 64 + rt * 16 + quad * 4 + r;
      const int rglob = r0 + rowl;
      const int mN = rmaxs[rowl];
      const float qscale = (mN > 0) ? 127.f / (float)mN : 0.f;
      const int bb = rglob >> 11;
      const int tt = rglob & (T_ - 1);
      const size_t obase = ((size_t)(bb * H_ + h) * T_ + tt) * D_;
      #pragma unroll
      for (int ct = 0; ct < 4; ++ct) {
        const int col = ch * 64 + ct * 16 + l15;
        float q = rintf((float)acc[rt][ct][r] * qscale);
        q = fminf(fmaxf(q, -128.f), 127.f);
        qkv[(size_t)wsel * R_ * C_ + obase + col] = (int8_t)q;
      }
      if (ch == 0 && l15 == 0) {
        float maxq = (float)mN * sx[rglob] * swv;
        sqkv[(size_t)wsel * R_ * H_ + (size_t)(bb * H_ + h) * T_ + tt] =
            fmaxf(maxq, EPSF) / 127.f;
      }
    }
}

// ---------------- V dequant+transpose: int8 [bh][t][d] -> PV-fragment layout ---------
// Output vT: per (bh, d, 32-key chunk c) one 128B row of 8 x 16B segs.
//   seg ((2g + d) & 7)     = hi bf16 of keys { kt*16 + g*4 + r : kt in 0..1, r in 0..3 }
//   seg ((2g + 1 + d) & 7) = lo bf16 of the same keys
// Rotation by d makes every wave64 ds_read_b128 conflict-free (each consecutive
// 8-lane group hits 8 distinct 16B slots). Unchanged from v11/v12 (verified).
__global__ __launch_bounds__(256) void vtrans_kernel(
    const int8_t* __restrict__ vq, const float* __restrict__ sv,
    short* __restrict__ vT)
{
  const int bh = blockIdx.y;
  const int s0 = blockIdx.x * 64;
  const int tid = (int)threadIdx.x;
  __shared__ __align__(16) int8_t Vs[64][144];
  __shared__ float svs[64];
  const int8_t* vbase = vq + ((size_t)bh * T_ + s0) * D_;
  #pragma unroll
  for (int it = 0; it < 2; ++it) {
    int idx = tid + it * 256;
    int row = idx >> 3, seg = idx & 7;
    *(uint4*)(&Vs[row][seg * 16]) = *(const uint4*)(vbase + row * 128 + seg * 16);
  }
  if (tid < 64) svs[tid] = sv[(size_t)bh * T_ + s0 + tid];
  __syncthreads();
  const int d    = tid >> 1;
  const int half = tid & 1;            // which 32-key chunk within this block
  const int kh   = half * 32;
  uint32_t oh[16], ol[16];
  #pragma unroll
  for (int i = 0; i < 32; i += 2) {
    const int k0 = kh + i, k1 = kh + i + 1;
    float v0 = (float)(int)Vs[k0][d] * svs[k0];
    float v1 = (float)(int)Vs[k1][d] * svs[k1];
    short h0 = f2bf(v0), h1 = f2bf(v1);
    short l0 = f2bf(v0 - bf2f(h0)), l1 = f2bf(v1 - bf2f(h1));
    oh[i >> 1] = (uint32_t)(uint16_t)h0 | ((uint32_t)(uint16_t)h1 << 16);
    ol[i >> 1] = (uint32_t)(uint16_t)l0 | ((uint32_t)(uint16_t)l1 << 16);
  }
  const int c = (s0 >> 5) + half;      // global 32-key chunk index (0..63)
  char* out = (char*)vT + ((((size_t)bh * 128 + d) * 64 + (size_t)c) << 7);
  const int par = d & 7;
  #pragma unroll
  for (int g = 0; g < 4; ++g) {
    uint4 hi, lo;
    hi.x = oh[2 * g];     hi.y = oh[2 * g + 1];
    hi.z = oh[2 * g + 8]; hi.w = oh[2 * g + 9];
    lo.x = ol[2 * g];     lo.y = ol[2 * g + 1];
    lo.z = ol[2 * g + 8]; lo.w = ol[2 * g + 9];
    *(uint4*)(out + (((2 * g + par) & 7) << 4))     = hi;
    *(uint4*)(out + (((2 * g + 1 + par) & 7) << 4)) = lo;
  }
}

// ---------------- fused attention v13: counted-vmcnt pipeline (T3/T4) ----------------
// UNCHANGED from measured-best (153.7-155.0us, Mfma 28.6 / VALU 37.2). See R5 notes.
__global__ __launch_bounds__(256, 2) void attn_mfma_kernel(
    const int8_t* __restrict__ qq, const int8_t* __restrict__ kq,
    const float* __restrict__ sq, const float* __restrict__ sk,
    const short* __restrict__ vT,
    int8_t* __restrict__ yq, float* __restrict__ sy)
{
  const int bh  = blockIdx.x;
  const int t0  = blockIdx.y * 128;
  const int tid = (int)threadIdx.x;
  const int w    = tid >> 6;           // 4 waves
  const int lane = tid & 63;
  const int quad = lane >> 4;
  const int l15  = lane & 15;

  // LDS: K bufs 3x4KB [0,12288); V bufs 3x16KB [12288,61440); sks [61440,69632)
  __shared__ __align__(16) char smem[69632];
  float* sks = (float*)(smem + 61440);

  const int qrow0 = t0 + 32 * w;

  const int8_t* kq_bh = kq + (size_t)bh * T_ * D_;
  const char*   vb    = (const char*)vT + ((size_t)bh << 20);

  const int kslot = w * 64 + lane;               // 0..255
  const int kkey  = kslot >> 3;                  // 0..31
  const int ksrc  = ((kslot & 7) ^ (kkey & 7)) * 16;
  auto stageK = [&](int buf, int cc) {
    dma16(kq_bh + (size_t)(cc * 32 + kkey) * 128 + ksrc,
          smem + buf * 4096 + (w * 64) * 16);
  };

  const size_t vlane = (size_t)(w * 32 + (lane >> 3)) * 8192 + (size_t)((lane & 7) * 16);
  auto stageV = [&](int buf, int cc) {
    char* dst = smem + 12288 + buf * 16384 + (w * 32) * 128;
    const char* src = vb + vlane + (size_t)cc * 128;
    #pragma unroll
    for (int j = 0; j < 4; ++j)
      dma16(src + (size_t)(j * 8) * 8192, dst + j * 1024);
  };

  {
    const float* skg = sk + (size_t)bh * T_;
    dma16(skg + (w * 2 + 0) * 256 + lane * 4, smem + 61440 + (w * 2 + 0) * 1024);
    dma16(skg + (w * 2 + 1) * 256 + lane * 4, smem + 61440 + (w * 2 + 1) * 1024);
  }
  stageK(0, 0);
  stageV(0, 0);

  i32x4 qf[2][2];
  #pragma unroll
  for (int qt = 0; qt < 2; ++qt)
    #pragma unroll
    for (int hf = 0; hf < 2; ++hf)
      qf[qt][hf] = *(const i32x4*)(qq + ((size_t)bh * T_ + qrow0 + qt * 16 + l15) * D_ +
                                   hf * 64 + quad * 16);
  float f0[2];
  #pragma unroll
  for (int qt = 0; qt < 2; ++qt)
    f0[qt] = sq[(size_t)bh * T_ + qrow0 + qt * 16 + l15] * INV_SQRT_D;

  __syncthreads();   // sks + chunk-0 visible before pass 1

  const int8_t* kqb = kq_bh + (size_t)(l15 * D_ + quad * 16);

  // ---- pass 1: exact rowmax of c*sk; global K stream, sk from LDS, no barriers ----
  float rx[2][4];
  #pragma unroll
  for (int qt = 0; qt < 2; ++qt)
    #pragma unroll
    for (int r = 0; r < 4; ++r) rx[qt][r] = -3e38f;

  for (int s0 = 0; s0 < T_; s0 += 64) {
    #pragma unroll
    for (int kt = 0; kt < 4; ++kt) {
      const f32x4 skv = *(const f32x4*)(sks + s0 + kt * 16 + quad * 4);
      const i32x4 ka = *(const i32x4*)(kqb + (size_t)(s0 + kt * 16) * D_);
      const i32x4 kb = *(const i32x4*)(kqb + (size_t)(s0 + kt * 16) * D_ + 64);
      #pragma unroll
      for (int qt = 0; qt < 2; ++qt) {
        i32x4 c = i32x4{0, 0, 0, 0};
        c = mfma_i8(ka, qf[qt][0], c);
        c = mfma_i8(kb, qf[qt][1], c);
        #pragma unroll
        for (int r = 0; r < 4; ++r)
          rx[qt][r] = fmaxf(rx[qt][r], (float)c[r] * skv[r]);
      }
    }
  }
  float f1[2], g[2];
  #pragma unroll
  for (int qt = 0; qt < 2; ++qt) {
    float m = fmaxf(fmaxf(rx[qt][0], rx[qt][1]), fmaxf(rx[qt][2], rx[qt][3]));
    m = fmaxf(m, __shfl_xor(m, 16, 64));
    m = fmaxf(m, __shfl_xor(m, 32, 64));
    f1[qt] = f0[qt] * LOG2E;
    g[qt]  = LOG2_127 - (m * f0[qt]) * LOG2E;
  }

  // ---- pass 2: quantized softmax (in-register weights) + PV, 64 x 32-key chunks ----
  float zac[2][4] = {};
  f32x4 yacc[2][8];
  #pragma unroll
  for (int qt = 0; qt < 2; ++qt)
    #pragma unroll
    for (int dt = 0; dt < 8; ++dt) yacc[qt][dt] = f32x4{0.f, 0.f, 0.f, 0.f};

  const int seg_hi = ((2 * quad + l15) & 7) << 4;
  const int seg_lo = ((2 * quad + 1 + l15) & 7) << 4;

  int bc = 0, bn = 1;
  for (int c = 0; c < 64; ++c) {
    const int s0k = c * 32;
    if (c + 1 < 64) {
      stageK(bn, c + 1);
      stageV(bn, c + 1);
      asm volatile("s_waitcnt vmcnt(5)" ::: "memory");   // own chunk-c DMAs done
    } else {
      asm volatile("s_waitcnt vmcnt(0)" ::: "memory");
    }
    __builtin_amdgcn_s_barrier();                        // all waves' chunk-c done
    asm volatile("" ::: "memory");                       // pin reads after barrier

    const char* Kb = smem + bc * 4096;
    uint32_t wdw[2][2][2];
    #pragma unroll
    for (int kt = 0; kt < 2; ++kt) {
      const f32x4 skv = *(const f32x4*)(sks + s0k + kt * 16 + quad * 4);
      const int key = kt * 16 + l15;
      const i32x4 ka = *(const i32x4*)(Kb + key * 128 + ((quad ^ (key & 7)) << 4));
      const i32x4 kb = *(const i32x4*)(Kb + key * 128 + (((quad + 4) ^ (key & 7)) << 4));
      #pragma unroll
      for (int qt = 0; qt < 2; ++qt) {
        i32x4 cc = i32x4{0, 0, 0, 0};
        cc = mfma_i8(ka, qf[qt][0], cc);
        cc = mfma_i8(kb, qf[qt][1], cc);
        float wq_[4];
        #pragma unroll
        for (int r = 0; r < 4; ++r) {
          float t = (float)cc[r] * skv[r];
          float wu = fast_exp2(fmaf(t, f1[qt], g[qt]));  // = 127*exp(s-m)
          zac[qt][r] += wu;
          wq_[r] = rintf(wu);                            // integer in [0,127]
        }
        wdw[qt][kt][0] = (__float_as_uint(wq_[0]) >> 16) |
                         (__float_as_uint(wq_[1]) & 0xffff0000u);
        wdw[qt][kt][1] = (__float_as_uint(wq_[2]) >> 16) |
                         (__float_as_uint(wq_[3]) & 0xffff0000u);
      }
    }

    s16x8 wf[2];
    #pragma unroll
    for (int qt = 0; qt < 2; ++qt) {
      u32x4 tw;
      tw[0] = wdw[qt][0][0]; tw[1] = wdw[qt][0][1];
      tw[2] = wdw[qt][1][0]; tw[3] = wdw[qt][1][1];
      wf[qt] = __builtin_bit_cast(s16x8, tw);
    }

    const char* Vc = smem + 12288 + bc * 16384;
    __builtin_amdgcn_s_setprio(1);
    #pragma unroll
    for (int dt = 0; dt < 8; ++dt) {
      const char* rowp = Vc + (dt * 16 + l15) * 128;
      const s16x8 vh = *(const s16x8*)(rowp + seg_hi);
      const s16x8 vl = *(const s16x8*)(rowp + seg_lo);
      yacc[0][dt] = mfma_bf16(wf[0], vh, yacc[0][dt]);
      yacc[0][dt] = mfma_bf16(wf[0], vl, yacc[0][dt]);
      yacc[1][dt] = mfma_bf16(wf[1], vh, yacc[1][dt]);
      yacc[1][dt] = mfma_bf16(wf[1], vl, yacc[1][dt]);
    }
    __builtin_amdgcn_s_setprio(0);

    bc = bn; bn = (bn == 2) ? 0 : bn + 1;
  }

  // ---- epilogue: z reduce over quads, transpose to yacc's row layout, quantize ----
  float zq[2];
  #pragma unroll
  for (int qt = 0; qt < 2; ++qt) {
    float z = (zac[qt][0] + zac[qt][1]) + (zac[qt][2] + zac[qt][3]);
    z += __shfl_xor(z, 16, 64);
    z += __shfl_xor(z, 32, 64);
    zq[qt] = z;                       // all lanes: 127*Z for q = l15
  }

  const int b = bh >> 4;
  const int h = bh & 15;
  #pragma unroll
  for (int qt = 0; qt < 2; ++qt)
    #pragma unroll
    for (int r = 0; r < 4; ++r) {
      const float zr = __shfl(zq[qt], quad * 4 + r, 64);   // z for q = quad*4+r
      float ym = 0.f;
      #pragma unroll
      for (int dt = 0; dt < 8; ++dt) ym = fmaxf(ym, fabsf(yacc[qt][dt][r]));
      #pragma unroll
      for (int mm = 1; mm < 16; mm <<= 1) ym = fmaxf(ym, __shfl_xor(ym, mm, 64));
      const float invz = 1.f / zr;
      const float ymt = fmaxf(ym * invz, EPSF);
      const float fs = 127.f / ymt;
      const int tglob = t0 + 32 * w + qt * 16 + quad * 4 + r;
      const size_t rowbase = ((size_t)(b * T_ + tglob)) * C_ + h * D_;
      #pragma unroll
      for (int dt = 0; dt < 8; ++dt) {
        float yv = yacc[qt][dt][r] * invz;
        float qv = fminf(fmaxf(rintf(yv * fs), -128.f), 127.f);
        yq[rowbase + dt * 16 + l15] = (int8_t)qv;
      }
      if (l15 == 0)
        sy[(size_t)(b * T_ + tglob) * H_ + h] = ymt / 127.f;
    }
}

// ---------------- output projection v2: async-DMA double-buffered -------------------
// REVERTED to R6/528.4us form (1 __syncthreads per kc; counted-vmcnt variants both
// measured slower — see proj comment).
__global__ __launch_bounds__(256) void outproj_mfma_kernel(
    const int8_t* __restrict__ yq, const float* __restrict__ sy,
    const int8_t* __restrict__ Wt, const float* __restrict__ sw4,
    float* __restrict__ outp)
{
  const int n0  = blockIdx.x * 64;
  const int r0  = blockIdx.y * 128;
  const int tid = (int)threadIdx.x;
  const int wv   = tid >> 6;
  const int lane = tid & 63;
  const int quad = lane >> 4;
  const int l15  = lane & 15;
  const int rh   = wv >> 1, ch = wv & 1;
  const int8_t* Wm = Wt + (size_t)3 * C_ * C_;

  __shared__ __align__(16) char As[2][8192];   // 512 slots x 16B, swizzled
  __shared__ __align__(16) char Bs[2][4096];   // 256 slots x 16B, swizzled
  __shared__ float sYs[128][16];
  for (int idx = tid; idx < 128 * 16; idx += 256)
    sYs[idx >> 4][idx & 15] = sy[(size_t)(r0 + (idx >> 4)) * H_ + (idx & 15)];

  const int s0a   = wv * 128;
  const int rowA0 = (s0a + lane) >> 2;
  const int qdA0  = ((s0a + lane) & 3) ^ (rowA0 & 3);
  const int rowA1 = (s0a + 64 + lane) >> 2;
  const int qdA1  = ((s0a + 64 + lane) & 3) ^ (rowA1 & 3);
  const int sb    = wv * 64 + lane;
  const int colB  = sb >> 2;
  const int qdB   = (sb & 3) ^ (colB & 3);

  auto stage = [&](int bf, int k0) {
    dma16(yq + (size_t)(r0 + rowA0) * C_ + k0 + qdA0 * 16, &As[bf][(s0a) * 16]);
    dma16(yq + (size_t)(r0 + rowA1) * C_ + k0 + qdA1 * 16, &As[bf][(s0a + 64) * 16]);
    dma16(Wm + (size_t)(n0 + colB) * C_ + k0 + qdB * 16, &Bs[bf][(wv * 64) * 16]);
  };

  i32x4 iacc[4][2];
  f32x4 facc[4][2];
  #pragma unroll
  for (int i = 0; i < 4; ++i)
    #pragma unroll
    for (int j = 0; j < 2; ++j) { iacc[i][j] = i32x4{0,0,0,0}; facc[i][j] = f32x4{0.f,0.f,0.f,0.f}; }

  stage(0, 0);
  for (int kc = 0; kc < 32; ++kc) {
    __syncthreads();
    if (kc + 1 < 32) stage((kc + 1) & 1, (kc + 1) * 64);
    const char* Ab = As[kc & 1];
    const char* Bb = Bs[kc & 1];
    i32x4 a[4], b[2];
    #pragma unroll
    for (int rt = 0; rt < 4; ++rt) {
      const int row = rh * 64 + rt * 16 + l15;
      a[rt] = *(const i32x4*)(Ab + (row * 4 + (quad ^ (row & 3))) * 16);
    }
    #pragma unroll
    for (int ct = 0; ct < 2; ++ct) {
      const int col = ch * 32 + ct * 16 + l15;
      b[ct] = *(const i32x4*)(Bb + (col * 4 + (quad ^ (col & 3))) * 16);
    }
    #pragma unroll
    for (int rt = 0; rt < 4; ++rt)
      #pragma unroll
      for (int ct = 0; ct < 2; ++ct)
        iacc[rt][ct] = mfma_i8(a[rt], b[ct], iacc[rt][ct]);
    if (kc & 1) {
      const int hd = kc >> 1;
      #pragma unroll
      for (int rt = 0; rt < 4; ++rt)
        #pragma unroll
        for (int r = 0; r < 4; ++r) {
          const float s = sYs[rh * 64 + rt * 16 + quad * 4 + r][hd];
          #pragma unroll
          for (int ct = 0; ct < 2; ++ct)
            facc[rt][ct][r] += (float)iacc[rt][ct][r] * s;
        }
      #pragma unroll
      for (int rt = 0; rt < 4; ++rt)
        #pragma unroll
        for (int ct = 0; ct < 2; ++ct) iacc[rt][ct] = i32x4{0,0,0,0};
    }
  }
  const float swp = sw4[3];
  #pragma unroll
  for (int rt = 0; rt < 4; ++rt)
    #pragma unroll
    for (int r = 0; r < 4; ++r) {
      const int rowl = rh * 64 + rt * 16 + quad * 4 + r;
      #pragma unroll
      for (int ct = 0; ct < 2; ++ct)
        outp[(size_t)(r0 + rowl) * C_ + n0 + ch * 32 + ct * 16 + l15] =
            facc[rt][ct][r] * swp;
    }
}

// ---------------- final per-token act_quant: float4 in/out --------------------------
__global__ __launch_bounds__(256) void final_quant_kernel(
    const float* __restrict__ outp, float* __restrict__ out)
{
  const int r = blockIdx.x;
  const float4* xr = (const float4*)(outp + (size_t)r * C_);
  float am = 0.f;
  for (int j = threadIdx.x; j < C_ / 4; j += 256) {
    float4 v = xr[j];
    am = fmaxf(am, fmaxf(fmaxf(fabsf(v.x), fabsf(v.y)),
                         fmaxf(fabsf(v.z), fabsf(v.w))));
  }
  __shared__ float sm[256];
  sm[threadIdx.x] = am;
  __syncthreads();
  for (int o = 128; o > 0; o >>= 1) {
    if ((int)threadIdx.x < o) sm[threadIdx.x] = fmaxf(sm[threadIdx.x], sm[threadIdx.x + o]);
    __syncthreads();
  }
  const float m = fmaxf(sm[0], EPSF);
  const float scale = 127.f / m;
  const float inv = m / 127.f;
  float4* o4 = (float4*)(out + (size_t)r * C_);
  for (int j = threadIdx.x; j < C_ / 4; j += 256) {
    float4 v = xr[j];
    float4 o;
    o.x = fminf(fmaxf(rintf(v.x * scale), -128.f), 127.f) * inv;
    o.y = fminf(fmaxf(rintf(v.y * scale), -128.f), 127.f) * inv;
    o.z = fminf(fmaxf(rintf(v.z * scale), -128.f), 127.f) * inv;
    o.w = fminf(fmaxf(rintf(v.w * scale), -128.f), 127.f) * inv;
    o4[j] = o;
  }
}

} // namespace

extern "C" void kernel_launch(void* const* d_in, const int* in_sizes, int n_in,
                              void* d_out, int out_size, void* d_ws, size_t ws_size,
                              hipStream_t stream)
{
  (void)in_sizes; (void)n_in; (void)out_size; (void)ws_size;
  const float* x  = (const float*)d_in[0];
  const float* W0 = (const float*)d_in[1];
  const float* W1 = (const float*)d_in[2];
  const float* W2 = (const float*)d_in[3];
  const float* W3 = (const float*)d_in[4];

  char* ws = (char*)d_ws;
  double* wsum = (double*)(ws + OFF_WSUM);
  float*  swv  = (float*) (ws + OFF_SW);
  int8_t* Wt   = (int8_t*)(ws + OFF_WT);
  int8_t* xq   = (int8_t*)(ws + OFF_XQ);
  float*  sx   = (float*) (ws + OFF_SX);
  int8_t* qkv  = (int8_t*)(ws + OFF_QKV);
  float*  sqkv = (float*) (ws + OFF_SQKV);
  int8_t* yqp  = (int8_t*)(ws + OFF_YQ);
  float*  syp  = (float*) (ws + OFF_SY);
  float*  outp = (float*) (ws + OFF_OUTP);
  short*  vT   = (short*) (ws + OFF_VT);           // aliases outp

  hipMemsetAsync(d_ws, 0, 256, stream);
  hipLaunchKernelGGL(wabs_sum_kernel, dim3(256), dim3(256), 0, stream, W0, W1, W2, W3, wsum);
  hipLaunchKernelGGL(wquant_kernel, dim3(4096), dim3(256), 0, stream, W0, W1, W2, W3, wsum, Wt, swv);
  hipLaunchKernelGGL(xquant_kernel, dim3(R_), dim3(256), 0, stream, x, xq, sx);
  hipLaunchKernelGGL(proj_mfma_kernel, dim3(H_, R_ / 128, 3), dim3(256), 0, stream,
                     xq, sx, Wt, swv, qkv, sqkv);
  hipLaunchKernelGGL(vtrans_kernel, dim3(T_ / 64, B_ * H_), dim3(256), 0, stream,
                     qkv + (size_t)2 * R_ * C_, sqkv + (size_t)2 * R_ * H_, vT);
  hipLaunchKernelGGL(attn_mfma_kernel, dim3(B_ * H_, T_ / 128), dim3(256), 0, stream,
                     qkv, qkv + (size_t)R_ * C_,
                     sqkv, sqkv + (size_t)R_ * H_,
                     vT, yqp, syp);
  hipLaunchKernelGGL(outproj_mfma_kernel, dim3(C_ / 64, R_ / 128), dim3(256), 0, stream,
                     yqp, syp, Wt, swv, outp);
  hipLaunchKernelGGL(final_quant_kernel, dim3(R_), dim3(256), 0, stream, outp, (float*)d_out);
}

// Round 10
// 446.392 us; speedup vs baseline: 1.2158x; 1.0001x over previous
//
#include <hip/hip_runtime.h>
#include <stdint.h>

namespace {

constexpr int B_ = 2, T_ = 2048, C_ = 2048, H_ = 16, D_ = 128;
constexpr int R_ = B_ * T_;                 // 4096 token rows (b*T + t)
constexpr float EPSF = 1e-5f;
constexpr float INV_SQRT_D = 0.08838834764831845f;   // 1/sqrt(128)
constexpr float LOG2E = 1.4426950408889634f;
constexpr float LOG2_127 = 6.988684686772166f;

// ---- workspace layout (bytes) ----
constexpr size_t OFF_WSUM = 0;                                   // double[4]
constexpr size_t OFF_SW   = 64;                                  // float[4]
constexpr size_t OFF_WT   = 256;                                 // int8[4][C*C] ternary
constexpr size_t OFF_XQ   = OFF_WT   + (size_t)4 * C_ * C_;      // int8[R*C]
constexpr size_t OFF_SX   = OFF_XQ   + (size_t)R_ * C_;          // float[R]
constexpr size_t OFF_QKV  = OFF_SX   + (size_t)R_ * 4;           // int8[3][B*H*T*D]
constexpr size_t OFF_SQKV = OFF_QKV  + (size_t)3 * R_ * C_;      // float[3][B*H*T]
constexpr size_t OFF_YQ   = OFF_SQKV + (size_t)3 * R_ * H_ * 4;  // int8[R*C]
constexpr size_t OFF_SY   = OFF_YQ   + (size_t)R_ * C_;          // float[R*H]
constexpr size_t OFF_OUTP = OFF_SY   + (size_t)R_ * H_ * 4;      // float[R*C]
// vT (bf16 hi/lo interleaved PV-fragment layout, 33.55 MB) aliases OUTP (33.55 MB):
// dead before outproj writes outp (stream-ordered), so no extra workspace.
constexpr size_t OFF_VT   = OFF_OUTP;
// rmax (float[B*H*T] = 256KB) aliases XQ: xq is dead after proj (stream-ordered).

typedef int   i32x4 __attribute__((ext_vector_type(4)));
typedef short s16x8 __attribute__((ext_vector_type(8)));
typedef float f32x4 __attribute__((ext_vector_type(4)));
typedef unsigned int u32x4 __attribute__((ext_vector_type(4)));

__device__ __forceinline__ i32x4 mfma_i8(i32x4 a, i32x4 b, i32x4 c) {
  return __builtin_amdgcn_mfma_i32_16x16x64_i8(a, b, c, 0, 0, 0);
}
__device__ __forceinline__ f32x4 mfma_bf16(s16x8 a, s16x8 b, f32x4 c) {
  return __builtin_amdgcn_mfma_f32_16x16x32_bf16(a, b, c, 0, 0, 0);
}

// async global->LDS DMA, 16B per lane; LDS dest = wave-uniform base + lane*16
__device__ __forceinline__ void dma16(const void* g, void* l) {
  __builtin_amdgcn_global_load_lds(
      (const __attribute__((address_space(1))) void*)g,
      (__attribute__((address_space(3))) void*)l, 16, 0, 0);
}

#if __has_builtin(__builtin_amdgcn_exp2f)
__device__ __forceinline__ float fast_exp2(float x) { return __builtin_amdgcn_exp2f(x); }
#else
__device__ __forceinline__ float fast_exp2(float x) { return exp2f(x); }
#endif

// RTNE float->bf16 bits (matches numpy RTNE)
__device__ __forceinline__ short f2bf(float f) {
  union { float f; uint32_t u; } v; v.f = f;
  uint32_t r = v.u + 0x7fffu + ((v.u >> 16) & 1u);
  return (short)(r >> 16);
}
__device__ __forceinline__ float bf2f(short h) {
  union { uint32_t u; float f; } v; v.u = ((uint32_t)(uint16_t)h) << 16;
  return v.f;
}

// ---------------- mean(|W|): float4-vectorized (G13), double accum ------------------
__global__ __launch_bounds__(256) void wabs_sum_kernel(
    const float* __restrict__ W0, const float* __restrict__ W1,
    const float* __restrict__ W2, const float* __restrict__ W3,
    double* __restrict__ wsum)
{
  const int w   = blockIdx.x >> 6;
  const int blk = blockIdx.x & 63;
  const float* W = (w == 0) ? W0 : (w == 1) ? W1 : (w == 2) ? W2 : W3;
  const float4* W4 = (const float4*)W;
  const int n4 = (C_ * C_) / 4;
  double s = 0.0;
  for (int i = blk * 256 + (int)threadIdx.x; i < n4; i += 64 * 256) {
    float4 v = W4[i];
    s += (double)fabsf(v.x) + (double)fabsf(v.y) +
         (double)fabsf(v.z) + (double)fabsf(v.w);
  }
  __shared__ double sm[256];
  sm[threadIdx.x] = s;
  __syncthreads();
  for (int o = 128; o > 0; o >>= 1) {
    if ((int)threadIdx.x < o) sm[threadIdx.x] += sm[threadIdx.x + o];
    __syncthreads();
  }
  if (threadIdx.x == 0) atomicAdd(&wsum[w], sm[0]);
}

// ---------------- ternary weight quant: float4 load, packed int8x4 store ------------
__global__ __launch_bounds__(256) void wquant_kernel(
    const float* __restrict__ W0, const float* __restrict__ W1,
    const float* __restrict__ W2, const float* __restrict__ W3,
    const double* __restrict__ wsum, int8_t* __restrict__ Wt, float* __restrict__ sw)
{
  const int w = blockIdx.x >> 10;
  const float* W = (w == 0) ? W0 : (w == 1) ? W1 : (w == 2) ? W2 : W3;
  const int n = C_ * C_;
  const int n4 = n / 4;
  const float s = fmaxf((float)(wsum[w] * (1.0 / (double)n)), EPSF);
  const float4* W4 = (const float4*)W;
  uint32_t* dst4 = (uint32_t*)(Wt + (size_t)w * n);
  const int base = (blockIdx.x & 1023) * 256 + (int)threadIdx.x;
  for (int i = base; i < n4; i += 1024 * 256) {
    float4 v = W4[i];
    union { int8_t b[4]; uint32_t u; } pk;
    pk.b[0] = (int8_t)fminf(fmaxf(rintf(v.x / s), -1.f), 1.f);
    pk.b[1] = (int8_t)fminf(fmaxf(rintf(v.y / s), -1.f), 1.f);
    pk.b[2] = (int8_t)fminf(fmaxf(rintf(v.z / s), -1.f), 1.f);
    pk.b[3] = (int8_t)fminf(fmaxf(rintf(v.w / s), -1.f), 1.f);
    dst4[i] = pk.u;
  }
  if (base == 0) sw[w] = s;
}

// ---------------- per-token act_quant of x: float4 load, packed int8x4 store --------
__global__ __launch_bounds__(256) void xquant_kernel(
    const float* __restrict__ x, int8_t* __restrict__ xq, float* __restrict__ sx)
{
  const int r = blockIdx.x;
  const float4* xr = (const float4*)(x + (size_t)r * C_);
  float am = 0.f;
  for (int j = threadIdx.x; j < C_ / 4; j += 256) {
    float4 v = xr[j];
    am = fmaxf(am, fmaxf(fmaxf(fabsf(v.x), fabsf(v.y)),
                         fmaxf(fabsf(v.z), fabsf(v.w))));
  }
  __shared__ float sm[256];
  sm[threadIdx.x] = am;
  __syncthreads();
  for (int o = 128; o > 0; o >>= 1) {
    if ((int)threadIdx.x < o) sm[threadIdx.x] = fmaxf(sm[threadIdx.x], sm[threadIdx.x + o]);
    __syncthreads();
  }
  const float m = fmaxf(sm[0], EPSF);
  const float scale = 127.f / m;
  uint32_t* dst4 = (uint32_t*)(xq + (size_t)r * C_);
  for (int j = threadIdx.x; j < C_ / 4; j += 256) {
    float4 v = xr[j];
    union { int8_t b[4]; uint32_t u; } pk;
    pk.b[0] = (int8_t)fminf(fmaxf(rintf(v.x * scale), -128.f), 127.f);
    pk.b[1] = (int8_t)fminf(fmaxf(rintf(v.y * scale), -128.f), 127.f);
    pk.b[2] = (int8_t)fminf(fmaxf(rintf(v.z * scale), -128.f), 127.f);
    pk.b[3] = (int8_t)fminf(fmaxf(rintf(v.w * scale), -128.f), 127.f);
    dst4[j] = pk.u;
  }
  if (threadIdx.x == 0) sx[r] = m / 127.f;
}

// ---------------- q/k/v projection: i8 MFMA, async-DMA double-buffered LDS ----------
// R6/528.4us form (best measured; counted-vmcnt variants regressed, R7/R8).
__global__ __launch_bounds__(256) void proj_mfma_kernel(
    const int8_t* __restrict__ xq, const float* __restrict__ sx,
    const int8_t* __restrict__ Wt, const float* __restrict__ sw4,
    int8_t* __restrict__ qkv, float* __restrict__ sqkv)
{
  const int h    = blockIdx.x;
  const int r0   = blockIdx.y * 128;
  const int wsel = blockIdx.z;
  const int tid  = (int)threadIdx.x;
  const int wv   = tid >> 6;
  const int lane = tid & 63;
  const int quad = lane >> 4;
  const int l15  = lane & 15;
  const int rh   = wv >> 1, ch = wv & 1;
  const int8_t* Wm = Wt + (size_t)wsel * C_ * C_;

  __shared__ __align__(16) char As[2][8192];   // 512 slots x 16B, swizzled
  __shared__ __align__(16) char Bs[2][8192];
  __shared__ int rmaxs[128];
  if (tid < 128) rmaxs[tid] = 0;

  const int s0a   = wv * 128;
  const int rowA0 = (s0a + lane) >> 2;
  const int qdA0  = ((s0a + lane) & 3) ^ (rowA0 & 3);
  const int rowA1 = (s0a + 64 + lane) >> 2;
  const int qdA1  = ((s0a + 64 + lane) & 3) ^ (rowA1 & 3);

  auto stage = [&](int bf, int k0) {
    dma16(xq + (size_t)(r0 + rowA0) * C_ + k0 + qdA0 * 16, &As[bf][(s0a) * 16]);
    dma16(xq + (size_t)(r0 + rowA1) * C_ + k0 + qdA1 * 16, &As[bf][(s0a + 64) * 16]);
    dma16(Wm + (size_t)(h * 128 + rowA0) * C_ + k0 + qdA0 * 16, &Bs[bf][(s0a) * 16]);
    dma16(Wm + (size_t)(h * 128 + rowA1) * C_ + k0 + qdA1 * 16, &Bs[bf][(s0a + 64) * 16]);
  };

  i32x4 acc[4][4];
  #pragma unroll
  for (int i = 0; i < 4; ++i)
    #pragma unroll
    for (int j = 0; j < 4; ++j) acc[i][j] = i32x4{0, 0, 0, 0};

  stage(0, 0);
  for (int kc = 0; kc < 32; ++kc) {
    __syncthreads();
    if (kc + 1 < 32) stage((kc + 1) & 1, (kc + 1) * 64);
    const char* Ab = As[kc & 1];
    const char* Bb = Bs[kc & 1];
    i32x4 a[4], b[4];
    #pragma unroll
    for (int rt = 0; rt < 4; ++rt) {
      const int row = rh * 64 + rt * 16 + l15;
      a[rt] = *(const i32x4*)(Ab + (row * 4 + (quad ^ (row & 3))) * 16);
    }
    #pragma unroll
    for (int ct = 0; ct < 4; ++ct) {
      const int col = ch * 64 + ct * 16 + l15;
      b[ct] = *(const i32x4*)(Bb + (col * 4 + (quad ^ (col & 3))) * 16);
    }
    #pragma unroll
    for (int rt = 0; rt < 4; ++rt)
      #pragma unroll
      for (int ct = 0; ct < 4; ++ct)
        acc[rt][ct] = mfma_i8(a[rt], b[ct], acc[rt][ct]);
  }

  #pragma unroll
  for (int rt = 0; rt < 4; ++rt)
    #pragma unroll
    for (int r = 0; r < 4; ++r) {
      int m = 0;
      #pragma unroll
      for (int ct = 0; ct < 4; ++ct) {
        int v = acc[rt][ct][r];
        int av = v < 0 ? -v : v;
        m = m > av ? m : av;
      }
      #pragma unroll
      for (int mm = 1; mm < 16; mm <<= 1) {
        int o = __shfl_xor(m, mm, 64);
        m = m > o ? m : o;
      }
      if (l15 == 0) atomicMax(&rmaxs[rh * 64 + rt * 16 + quad * 4 + r], m);
    }
  __syncthreads();

  const float swv = sw4[wsel];
  #pragma unroll
  for (int rt = 0; rt < 4; ++rt)
    #pragma unroll
    for (int r = 0; r < 4; ++r) {
      const int rowl = rh * 64 + rt * 16 + quad * 4 + r;
      const int rglob = r0 + rowl;
      const int mN = rmaxs[rowl];
      const float qscale = (mN > 0) ? 127.f / (float)mN : 0.f;
      const int bb = rglob >> 11;
      const int tt = rglob & (T_ - 1);
      const size_t obase = ((size_t)(bb * H_ + h) * T_ + tt) * D_;
      #pragma unroll
      for (int ct = 0; ct < 4; ++ct) {
        const int col = ch * 64 + ct * 16 + l15;
        float q = rintf((float)acc[rt][ct][r] * qscale);
        q = fminf(fmaxf(q, -128.f), 127.f);
        qkv[(size_t)wsel * R_ * C_ + obase + col] = (int8_t)q;
      }
      if (ch == 0 && l15 == 0) {
        float maxq = (float)mN * sx[rglob] * swv;
        sqkv[(size_t)wsel * R_ * H_ + (size_t)(bb * H_ + h) * T_ + tt] =
            fmaxf(maxq, EPSF) / 127.f;
      }
    }
}

// ---------------- rowmax kernel: hoisted attn pass 1 (bit-exact) --------------------
// R9: attn's pass 1 had 4 waves re-streaming the IDENTICAL full K (4x redundant L2
// traffic) inside a 2-blocks/CU kernel. Hoisted to a standalone high-occupancy
// reduction-GEMM: grid (32 bh, 32 qtiles) = 1024 blocks, 4 waves each covering a
// disjoint K-quarter for 64 q-rows; partial maxima combined via LDS. Identical i8
// MFMA products, identical c*sk floats; fmax is exact/associative -> m bit-identical.
__global__ __launch_bounds__(256) void rowmax_kernel(
    const int8_t* __restrict__ qq, const int8_t* __restrict__ kq,
    const float* __restrict__ sk, float* __restrict__ rmax)
{
  const int bh  = blockIdx.x;
  const int q0  = blockIdx.y * 64;
  const int tid = (int)threadIdx.x;
  const int w    = tid >> 6;
  const int lane = tid & 63;
  const int quad = lane >> 4;
  const int l15  = lane & 15;

  i32x4 qf[4][2];
  #pragma unroll
  for (int qt = 0; qt < 4; ++qt)
    #pragma unroll
    for (int hf = 0; hf < 2; ++hf)
      qf[qt][hf] = *(const i32x4*)(qq + ((size_t)bh * T_ + q0 + qt * 16 + l15) * D_ +
                                   hf * 64 + quad * 16);

  const int8_t* kqb = kq + (size_t)bh * T_ * D_ + (size_t)(l15 * D_ + quad * 16);
  const float*  skb = sk + (size_t)bh * T_ + quad * 4;

  float rx[4][4];
  #pragma unroll
  for (int qt = 0; qt < 4; ++qt)
    #pragma unroll
    for (int r = 0; r < 4; ++r) rx[qt][r] = -3e38f;

  const int sbase = w * 512;     // this wave's disjoint K-quarter
  for (int st = 0; st < 8; ++st) {
    const int s0 = sbase + st * 64;
    #pragma unroll
    for (int kt = 0; kt < 4; ++kt) {
      const f32x4 skv = *(const f32x4*)(skb + s0 + kt * 16);
      const i32x4 ka = *(const i32x4*)(kqb + (size_t)(s0 + kt * 16) * D_);
      const i32x4 kb = *(const i32x4*)(kqb + (size_t)(s0 + kt * 16) * D_ + 64);
      #pragma unroll
      for (int qt = 0; qt < 4; ++qt) {
        i32x4 c = i32x4{0, 0, 0, 0};
        c = mfma_i8(ka, qf[qt][0], c);
        c = mfma_i8(kb, qf[qt][1], c);
        #pragma unroll
        for (int r = 0; r < 4; ++r)
          rx[qt][r] = fmaxf(rx[qt][r], (float)c[r] * skv[r]);
      }
    }
  }

  __shared__ float wmx[4][4][16];
  #pragma unroll
  for (int qt = 0; qt < 4; ++qt) {
    float m = fmaxf(fmaxf(rx[qt][0], rx[qt][1]), fmaxf(rx[qt][2], rx[qt][3]));
    m = fmaxf(m, __shfl_xor(m, 16, 64));
    m = fmaxf(m, __shfl_xor(m, 32, 64));
    if (quad == 0) wmx[w][qt][l15] = m;
  }
  __syncthreads();
  if (tid < 64) {
    #pragma unroll
    for (int qt = 0; qt < 4; ++qt) {
      float mm = fmaxf(fmaxf(wmx[0][qt][l15], wmx[1][qt][l15]),
                       fmaxf(wmx[2][qt][l15], wmx[3][qt][l15]));
      if (quad == 0) rmax[(size_t)bh * T_ + q0 + qt * 16 + l15] = mm;
    }
  }
}

// ---------------- V dequant+transpose: int8 [bh][t][d] -> PV-fragment layout ---------
__global__ __launch_bounds__(256) void vtrans_kernel(
    const int8_t* __restrict__ vq, const float* __restrict__ sv,
    short* __restrict__ vT)
{
  const int bh = blockIdx.y;
  const int s0 = blockIdx.x * 64;
  const int tid = (int)threadIdx.x;
  __shared__ __align__(16) int8_t Vs[64][144];
  __shared__ float svs[64];
  const int8_t* vbase = vq + ((size_t)bh * T_ + s0) * D_;
  #pragma unroll
  for (int it = 0; it < 2; ++it) {
    int idx = tid + it * 256;
    int row = idx >> 3, seg = idx & 7;
    *(uint4*)(&Vs[row][seg * 16]) = *(const uint4*)(vbase + row * 128 + seg * 16);
  }
  if (tid < 64) svs[tid] = sv[(size_t)bh * T_ + s0 + tid];
  __syncthreads();
  const int d    = tid >> 1;
  const int half = tid & 1;            // which 32-key chunk within this block
  const int kh   = half * 32;
  uint32_t oh[16], ol[16];
  #pragma unroll
  for (int i = 0; i < 32; i += 2) {
    const int k0 = kh + i, k1 = kh + i + 1;
    float v0 = (float)(int)Vs[k0][d] * svs[k0];
    float v1 = (float)(int)Vs[k1][d] * svs[k1];
    short h0 = f2bf(v0), h1 = f2bf(v1);
    short l0 = f2bf(v0 - bf2f(h0)), l1 = f2bf(v1 - bf2f(h1));
    oh[i >> 1] = (uint32_t)(uint16_t)h0 | ((uint32_t)(uint16_t)h1 << 16);
    ol[i >> 1] = (uint32_t)(uint16_t)l0 | ((uint32_t)(uint16_t)l1 << 16);
  }
  const int c = (s0 >> 5) + half;      // global 32-key chunk index (0..63)
  char* out = (char*)vT + ((((size_t)bh * 128 + d) * 64 + (size_t)c) << 7);
  const int par = d & 7;
  #pragma unroll
  for (int g = 0; g < 4; ++g) {
    uint4 hi, lo;
    hi.x = oh[2 * g];     hi.y = oh[2 * g + 1];
    hi.z = oh[2 * g + 8]; hi.w = oh[2 * g + 9];
    lo.x = ol[2 * g];     lo.y = ol[2 * g + 1];
    lo.z = ol[2 * g + 8]; lo.w = ol[2 * g + 9];
    *(uint4*)(out + (((2 * g + par) & 7) << 4))     = hi;
    *(uint4*)(out + (((2 * g + 1 + par) & 7) << 4)) = lo;
  }
}

// ---------------- fused attention v14: pass-2 only (rowmax hoisted) ------------------
// v13's counted-vmcnt pipeline, with pass 1 removed (m read from rmax[]). All pass-2
// arithmetic byte-identical to v13 (measured 153.7-155.0us with pass 1 included).
__global__ __launch_bounds__(256, 2) void attn_mfma_kernel(
    const int8_t* __restrict__ qq, const int8_t* __restrict__ kq,
    const float* __restrict__ sq, const float* __restrict__ sk,
    const short* __restrict__ vT, const float* __restrict__ rmax,
    int8_t* __restrict__ yq, float* __restrict__ sy)
{
  const int bh  = blockIdx.x;
  const int t0  = blockIdx.y * 128;
  const int tid = (int)threadIdx.x;
  const int w    = tid >> 6;           // 4 waves
  const int lane = tid & 63;
  const int quad = lane >> 4;
  const int l15  = lane & 15;

  // LDS: K bufs 3x4KB [0,12288); V bufs 3x16KB [12288,61440); sks [61440,69632)
  __shared__ __align__(16) char smem[69632];
  float* sks = (float*)(smem + 61440);

  const int qrow0 = t0 + 32 * w;

  const int8_t* kq_bh = kq + (size_t)bh * T_ * D_;
  const char*   vb    = (const char*)vT + ((size_t)bh << 20);

  const int kslot = w * 64 + lane;               // 0..255
  const int kkey  = kslot >> 3;                  // 0..31
  const int ksrc  = ((kslot & 7) ^ (kkey & 7)) * 16;
  auto stageK = [&](int buf, int cc) {
    dma16(kq_bh + (size_t)(cc * 32 + kkey) * 128 + ksrc,
          smem + buf * 4096 + (w * 64) * 16);
  };

  const size_t vlane = (size_t)(w * 32 + (lane >> 3)) * 8192 + (size_t)((lane & 7) * 16);
  auto stageV = [&](int buf, int cc) {
    char* dst = smem + 12288 + buf * 16384 + (w * 32) * 128;
    const char* src = vb + vlane + (size_t)cc * 128;
    #pragma unroll
    for (int j = 0; j < 4; ++j)
      dma16(src + (size_t)(j * 8) * 8192, dst + j * 1024);
  };

  {
    const float* skg = sk + (size_t)bh * T_;
    dma16(skg + (w * 2 + 0) * 256 + lane * 4, smem + 61440 + (w * 2 + 0) * 1024);
    dma16(skg + (w * 2 + 1) * 256 + lane * 4, smem + 61440 + (w * 2 + 1) * 1024);
  }
  stageK(0, 0);
  stageV(0, 0);

  i32x4 qf[2][2];
  #pragma unroll
  for (int qt = 0; qt < 2; ++qt)
    #pragma unroll
    for (int hf = 0; hf < 2; ++hf)
      qf[qt][hf] = *(const i32x4*)(qq + ((size_t)bh * T_ + qrow0 + qt * 16 + l15) * D_ +
                                   hf * 64 + quad * 16);
  float f0[2];
  #pragma unroll
  for (int qt = 0; qt < 2; ++qt)
    f0[qt] = sq[(size_t)bh * T_ + qrow0 + qt * 16 + l15] * INV_SQRT_D;

  __syncthreads();   // sks + chunk-0 visible

  // m from hoisted rowmax kernel (bit-identical value); f1/g ops identical to v13.
  float f1[2], g[2];
  #pragma unroll
  for (int qt = 0; qt < 2; ++qt) {
    const float m = rmax[(size_t)bh * T_ + qrow0 + qt * 16 + l15];
    f1[qt] = f0[qt] * LOG2E;
    g[qt]  = LOG2_127 - (m * f0[qt]) * LOG2E;
  }

  // ---- pass 2: quantized softmax (in-register weights) + PV, 64 x 32-key chunks ----
  float zac[2][4] = {};
  f32x4 yacc[2][8];
  #pragma unroll
  for (int qt = 0; qt < 2; ++qt)
    #pragma unroll
    for (int dt = 0; dt < 8; ++dt) yacc[qt][dt] = f32x4{0.f, 0.f, 0.f, 0.f};

  const int seg_hi = ((2 * quad + l15) & 7) << 4;
  const int seg_lo = ((2 * quad + 1 + l15) & 7) << 4;

  int bc = 0, bn = 1;
  for (int c = 0; c < 64; ++c) {
    const int s0k = c * 32;
    if (c + 1 < 64) {
      stageK(bn, c + 1);
      stageV(bn, c + 1);
      asm volatile("s_waitcnt vmcnt(5)" ::: "memory");   // own chunk-c DMAs done
    } else {
      asm volatile("s_waitcnt vmcnt(0)" ::: "memory");
    }
    __builtin_amdgcn_s_barrier();                        // all waves' chunk-c done
    asm volatile("" ::: "memory");                       // pin reads after barrier

    const char* Kb = smem + bc * 4096;
    uint32_t wdw[2][2][2];
    #pragma unroll
    for (int kt = 0; kt < 2; ++kt) {
      const f32x4 skv = *(const f32x4*)(sks + s0k + kt * 16 + quad * 4);
      const int key = kt * 16 + l15;
      const i32x4 ka = *(const i32x4*)(Kb + key * 128 + ((quad ^ (key & 7)) << 4));
      const i32x4 kb = *(const i32x4*)(Kb + key * 128 + (((quad + 4) ^ (key & 7)) << 4));
      #pragma unroll
      for (int qt = 0; qt < 2; ++qt) {
        i32x4 cc = i32x4{0, 0, 0, 0};
        cc = mfma_i8(ka, qf[qt][0], cc);
        cc = mfma_i8(kb, qf[qt][1], cc);
        float wq_[4];
        #pragma unroll
        for (int r = 0; r < 4; ++r) {
          float t = (float)cc[r] * skv[r];
          float wu = fast_exp2(fmaf(t, f1[qt], g[qt]));  // = 127*exp(s-m)
          zac[qt][r] += wu;
          wq_[r] = rintf(wu);                            // integer in [0,127]
        }
        wdw[qt][kt][0] = (__float_as_uint(wq_[0]) >> 16) |
                         (__float_as_uint(wq_[1]) & 0xffff0000u);
        wdw[qt][kt][1] = (__float_as_uint(wq_[2]) >> 16) |
                         (__float_as_uint(wq_[3]) & 0xffff0000u);
      }
    }

    s16x8 wf[2];
    #pragma unroll
    for (int qt = 0; qt < 2; ++qt) {
      u32x4 tw;
      tw[0] = wdw[qt][0][0]; tw[1] = wdw[qt][0][1];
      tw[2] = wdw[qt][1][0]; tw[3] = wdw[qt][1][1];
      wf[qt] = __builtin_bit_cast(s16x8, tw);
    }

    const char* Vc = smem + 12288 + bc * 16384;
    __builtin_amdgcn_s_setprio(1);
    #pragma unroll
    for (int dt = 0; dt < 8; ++dt) {
      const char* rowp = Vc + (dt * 16 + l15) * 128;
      const s16x8 vh = *(const s16x8*)(rowp + seg_hi);
      const s16x8 vl = *(const s16x8*)(rowp + seg_lo);
      yacc[0][dt] = mfma_bf16(wf[0], vh, yacc[0][dt]);
      yacc[0][dt] = mfma_bf16(wf[0], vl, yacc[0][dt]);
      yacc[1][dt] = mfma_bf16(wf[1], vh, yacc[1][dt]);
      yacc[1][dt] = mfma_bf16(wf[1], vl, yacc[1][dt]);
    }
    __builtin_amdgcn_s_setprio(0);

    bc = bn; bn = (bn == 2) ? 0 : bn + 1;
  }

  // ---- epilogue: z reduce over quads, transpose to yacc's row layout, quantize ----
  float zq[2];
  #pragma unroll
  for (int qt = 0; qt < 2; ++qt) {
    float z = (zac[qt][0] + zac[qt][1]) + (zac[qt][2] + zac[qt][3]);
    z += __shfl_xor(z, 16, 64);
    z += __shfl_xor(z, 32, 64);
    zq[qt] = z;                       // all lanes: 127*Z for q = l15
  }

  const int b = bh >> 4;
  const int h = bh & 15;
  #pragma unroll
  for (int qt = 0; qt < 2; ++qt)
    #pragma unroll
    for (int r = 0; r < 4; ++r) {
      const float zr = __shfl(zq[qt], quad * 4 + r, 64);   // z for q = quad*4+r
      float ym = 0.f;
      #pragma unroll
      for (int dt = 0; dt < 8; ++dt) ym = fmaxf(ym, fabsf(yacc[qt][dt][r]));
      #pragma unroll
      for (int mm = 1; mm < 16; mm <<= 1) ym = fmaxf(ym, __shfl_xor(ym, mm, 64));
      const float invz = 1.f / zr;
      const float ymt = fmaxf(ym * invz, EPSF);
      const float fs = 127.f / ymt;
      const int tglob = t0 + 32 * w + qt * 16 + quad * 4 + r;
      const size_t rowbase = ((size_t)(b * T_ + tglob)) * C_ + h * D_;
      #pragma unroll
      for (int dt = 0; dt < 8; ++dt) {
        float yv = yacc[qt][dt][r] * invz;
        float qv = fminf(fmaxf(rintf(yv * fs), -128.f), 127.f);
        yq[rowbase + dt * 16 + l15] = (int8_t)qv;
      }
      if (l15 == 0)
        sy[(size_t)(b * T_ + tglob) * H_ + h] = ymt / 127.f;
    }
}

// ---------------- output projection v2: async-DMA double-buffered (R6 form) ---------
__global__ __launch_bounds__(256) void outproj_mfma_kernel(
    const int8_t* __restrict__ yq, const float* __restrict__ sy,
    const int8_t* __restrict__ Wt, const float* __restrict__ sw4,
    float* __restrict__ outp)
{
  const int n0  = blockIdx.x * 64;
  const int r0  = blockIdx.y * 128;
  const int tid = (int)threadIdx.x;
  const int wv   = tid >> 6;
  const int lane = tid & 63;
  const int quad = lane >> 4;
  const int l15  = lane & 15;
  const int rh   = wv >> 1, ch = wv & 1;
  const int8_t* Wm = Wt + (size_t)3 * C_ * C_;

  __shared__ __align__(16) char As[2][8192];   // 512 slots x 16B, swizzled
  __shared__ __align__(16) char Bs[2][4096];   // 256 slots x 16B, swizzled
  __shared__ float sYs[128][16];
  for (int idx = tid; idx < 128 * 16; idx += 256)
    sYs[idx >> 4][idx & 15] = sy[(size_t)(r0 + (idx >> 4)) * H_ + (idx & 15)];

  const int s0a   = wv * 128;
  const int rowA0 = (s0a + lane) >> 2;
  const int qdA0  = ((s0a + lane) & 3) ^ (rowA0 & 3);
  const int rowA1 = (s0a + 64 + lane) >> 2;
  const int qdA1  = ((s0a + 64 + lane) & 3) ^ (rowA1 & 3);
  const int sb    = wv * 64 + lane;
  const int colB  = sb >> 2;
  const int qdB   = (sb & 3) ^ (colB & 3);

  auto stage = [&](int bf, int k0) {
    dma16(yq + (size_t)(r0 + rowA0) * C_ + k0 + qdA0 * 16, &As[bf][(s0a) * 16]);
    dma16(yq + (size_t)(r0 + rowA1) * C_ + k0 + qdA1 * 16, &As[bf][(s0a + 64) * 16]);
    dma16(Wm + (size_t)(n0 + colB) * C_ + k0 + qdB * 16, &Bs[bf][(wv * 64) * 16]);
  };

  i32x4 iacc[4][2];
  f32x4 facc[4][2];
  #pragma unroll
  for (int i = 0; i < 4; ++i)
    #pragma unroll
    for (int j = 0; j < 2; ++j) { iacc[i][j] = i32x4{0,0,0,0}; facc[i][j] = f32x4{0.f,0.f,0.f,0.f}; }

  stage(0, 0);
  for (int kc = 0; kc < 32; ++kc) {
    __syncthreads();
    if (kc + 1 < 32) stage((kc + 1) & 1, (kc + 1) * 64);
    const char* Ab = As[kc & 1];
    const char* Bb = Bs[kc & 1];
    i32x4 a[4], b[2];
    #pragma unroll
    for (int rt = 0; rt < 4; ++rt) {
      const int row = rh * 64 + rt * 16 + l15;
      a[rt] = *(const i32x4*)(Ab + (row * 4 + (quad ^ (row & 3))) * 16);
    }
    #pragma unroll
    for (int ct = 0; ct < 2; ++ct) {
      const int col = ch * 32 + ct * 16 + l15;
      b[ct] = *(const i32x4*)(Bb + (col * 4 + (quad ^ (col & 3))) * 16);
    }
    #pragma unroll
    for (int rt = 0; rt < 4; ++rt)
      #pragma unroll
      for (int ct = 0; ct < 2; ++ct)
        iacc[rt][ct] = mfma_i8(a[rt], b[ct], iacc[rt][ct]);
    if (kc & 1) {
      const int hd = kc >> 1;
      #pragma unroll
      for (int rt = 0; rt < 4; ++rt)
        #pragma unroll
        for (int r = 0; r < 4; ++r) {
          const float s = sYs[rh * 64 + rt * 16 + quad * 4 + r][hd];
          #pragma unroll
          for (int ct = 0; ct < 2; ++ct)
            facc[rt][ct][r] += (float)iacc[rt][ct][r] * s;
        }
      #pragma unroll
      for (int rt = 0; rt < 4; ++rt)
        #pragma unroll
        for (int ct = 0; ct < 2; ++ct) iacc[rt][ct] = i32x4{0,0,0,0};
    }
  }
  const float swp = sw4[3];
  #pragma unroll
  for (int rt = 0; rt < 4; ++rt)
    #pragma unroll
    for (int r = 0; r < 4; ++r) {
      const int rowl = rh * 64 + rt * 16 + quad * 4 + r;
      #pragma unroll
      for (int ct = 0; ct < 2; ++ct)
        outp[(size_t)(r0 + rowl) * C_ + n0 + ch * 32 + ct * 16 + l15] =
            facc[rt][ct][r] * swp;
    }
}

// ---------------- final per-token act_quant: float4 in/out --------------------------
__global__ __launch_bounds__(256) void final_quant_kernel(
    const float* __restrict__ outp, float* __restrict__ out)
{
  const int r = blockIdx.x;
  const float4* xr = (const float4*)(outp + (size_t)r * C_);
  float am = 0.f;
  for (int j = threadIdx.x; j < C_ / 4; j += 256) {
    float4 v = xr[j];
    am = fmaxf(am, fmaxf(fmaxf(fabsf(v.x), fabsf(v.y)),
                         fmaxf(fabsf(v.z), fabsf(v.w))));
  }
  __shared__ float sm[256];
  sm[threadIdx.x] = am;
  __syncthreads();
  for (int o = 128; o > 0; o >>= 1) {
    if ((int)threadIdx.x < o) sm[threadIdx.x] = fmaxf(sm[threadIdx.x], sm[threadIdx.x + o]);
    __syncthreads();
  }
  const float m = fmaxf(sm[0], EPSF);
  const float scale = 127.f / m;
  const float inv = m / 127.f;
  float4* o4 = (float4*)(out + (size_t)r * C_);
  for (int j = threadIdx.x; j < C_ / 4; j += 256) {
    float4 v = xr[j];
    float4 o;
    o.x = fminf(fmaxf(rintf(v.x * scale), -128.f), 127.f) * inv;
    o.y = fminf(fmaxf(rintf(v.y * scale), -128.f), 127.f) * inv;
    o.z = fminf(fmaxf(rintf(v.z * scale), -128.f), 127.f) * inv;
    o.w = fminf(fmaxf(rintf(v.w * scale), -128.f), 127.f) * inv;
    o4[j] = o;
  }
}

} // namespace

extern "C" void kernel_launch(void* const* d_in, const int* in_sizes, int n_in,
                              void* d_out, int out_size, void* d_ws, size_t ws_size,
                              hipStream_t stream)
{
  (void)in_sizes; (void)n_in; (void)out_size; (void)ws_size;
  const float* x  = (const float*)d_in[0];
  const float* W0 = (const float*)d_in[1];
  const float* W1 = (const float*)d_in[2];
  const float* W2 = (const float*)d_in[3];
  const float* W3 = (const float*)d_in[4];

  char* ws = (char*)d_ws;
  double* wsum = (double*)(ws + OFF_WSUM);
  float*  swv  = (float*) (ws + OFF_SW);
  int8_t* Wt   = (int8_t*)(ws + OFF_WT);
  int8_t* xq   = (int8_t*)(ws + OFF_XQ);
  float*  sx   = (float*) (ws + OFF_SX);
  int8_t* qkv  = (int8_t*)(ws + OFF_QKV);
  float*  sqkv = (float*) (ws + OFF_SQKV);
  int8_t* yqp  = (int8_t*)(ws + OFF_YQ);
  float*  syp  = (float*) (ws + OFF_SY);
  float*  outp = (float*) (ws + OFF_OUTP);
  short*  vT   = (short*) (ws + OFF_VT);           // aliases outp
  float*  rmx  = (float*) (ws + OFF_XQ);           // aliases xq (dead after proj)

  hipMemsetAsync(d_ws, 0, 256, stream);
  hipLaunchKernelGGL(wabs_sum_kernel, dim3(256), dim3(256), 0, stream, W0, W1, W2, W3, wsum);
  hipLaunchKernelGGL(wquant_kernel, dim3(4096), dim3(256), 0, stream, W0, W1, W2, W3, wsum, Wt, swv);
  hipLaunchKernelGGL(xquant_kernel, dim3(R_), dim3(256), 0, stream, x, xq, sx);
  hipLaunchKernelGGL(proj_mfma_kernel, dim3(H_, R_ / 128, 3), dim3(256), 0, stream,
                     xq, sx, Wt, swv, qkv, sqkv);
  hipLaunchKernelGGL(rowmax_kernel, dim3(B_ * H_, T_ / 64), dim3(256), 0, stream,
                     qkv, qkv + (size_t)R_ * C_, sqkv + (size_t)R_ * H_, rmx);
  hipLaunchKernelGGL(vtrans_kernel, dim3(T_ / 64, B_ * H_), dim3(256), 0, stream,
                     qkv + (size_t)2 * R_ * C_, sqkv + (size_t)2 * R_ * H_, vT);
  hipLaunchKernelGGL(attn_mfma_kernel, dim3(B_ * H_, T_ / 128), dim3(256), 0, stream,
                     qkv, qkv + (size_t)R_ * C_,
                     sqkv, sqkv + (size_t)R_ * H_,
                     vT, rmx, yqp, syp);
  hipLaunchKernelGGL(outproj_mfma_kernel, dim3(C_ / 64, R_ / 128), dim3(256), 0, stream,
                     yqp, syp, Wt, swv, outp);
  hipLaunchKernelGGL(final_quant_kernel, dim3(R_), dim3(256), 0, stream, outp, (float*)d_out);
}

// Round 11
// 421.021 us; speedup vs baseline: 1.2890x; 1.0603x over previous
//
#include <hip/hip_runtime.h>
#include <stdint.h>

namespace {

constexpr int B_ = 2, T_ = 2048, C_ = 2048, H_ = 16, D_ = 128;
constexpr int R_ = B_ * T_;                 // 4096 token rows (b*T + t)
constexpr float EPSF = 1e-5f;
constexpr float INV_SQRT_D = 0.08838834764831845f;   // 1/sqrt(128)
constexpr float LOG2E = 1.4426950408889634f;
constexpr float LOG2_127 = 6.988684686772166f;

// ---- workspace layout (bytes) ----
constexpr size_t OFF_WSUM = 0;                                   // double[4]
constexpr size_t OFF_SW   = 64;                                  // float[4]
constexpr size_t OFF_WT   = 256;                                 // int8[4][C*C] ternary
constexpr size_t OFF_XQ   = OFF_WT   + (size_t)4 * C_ * C_;      // int8[R*C]
constexpr size_t OFF_SX   = OFF_XQ   + (size_t)R_ * C_;          // float[R]
constexpr size_t OFF_QKV  = OFF_SX   + (size_t)R_ * 4;           // int8[3][B*H*T*D]
constexpr size_t OFF_SQKV = OFF_QKV  + (size_t)3 * R_ * C_;      // float[3][B*H*T]
constexpr size_t OFF_YQ   = OFF_SQKV + (size_t)3 * R_ * H_ * 4;  // int8[R*C]
constexpr size_t OFF_SY   = OFF_YQ   + (size_t)R_ * C_;          // float[R*H]
constexpr size_t OFF_OUTP = OFF_SY   + (size_t)R_ * H_ * 4;      // float[R*C]
// vT (bf16 hi/lo interleaved PV-fragment layout, 33.55 MB) aliases OUTP (33.55 MB):
// dead before outproj writes outp (stream-ordered), so no extra workspace.
constexpr size_t OFF_VT   = OFF_OUTP;
// rmax (float[B*H*T] = 256KB) aliases XQ: xq is dead after proj (stream-ordered).

typedef int   i32x4 __attribute__((ext_vector_type(4)));
typedef short s16x8 __attribute__((ext_vector_type(8)));
typedef float f32x4 __attribute__((ext_vector_type(4)));
typedef unsigned int u32x4 __attribute__((ext_vector_type(4)));

__device__ __forceinline__ i32x4 mfma_i8(i32x4 a, i32x4 b, i32x4 c) {
  return __builtin_amdgcn_mfma_i32_16x16x64_i8(a, b, c, 0, 0, 0);
}
__device__ __forceinline__ f32x4 mfma_bf16(s16x8 a, s16x8 b, f32x4 c) {
  return __builtin_amdgcn_mfma_f32_16x16x32_bf16(a, b, c, 0, 0, 0);
}

// async global->LDS DMA, 16B per lane; LDS dest = wave-uniform base + lane*16
__device__ __forceinline__ void dma16(const void* g, void* l) {
  __builtin_amdgcn_global_load_lds(
      (const __attribute__((address_space(1))) void*)g,
      (__attribute__((address_space(3))) void*)l, 16, 0, 0);
}

#if __has_builtin(__builtin_amdgcn_exp2f)
__device__ __forceinline__ float fast_exp2(float x) { return __builtin_amdgcn_exp2f(x); }
#else
__device__ __forceinline__ float fast_exp2(float x) { return exp2f(x); }
#endif

// RTNE float->bf16 bits (matches numpy RTNE)
__device__ __forceinline__ short f2bf(float f) {
  union { float f; uint32_t u; } v; v.f = f;
  uint32_t r = v.u + 0x7fffu + ((v.u >> 16) & 1u);
  return (short)(r >> 16);
}
__device__ __forceinline__ float bf2f(short h) {
  union { uint32_t u; float f; } v; v.u = ((uint32_t)(uint16_t)h) << 16;
  return v.f;
}

// ---------------- mean(|W|): float4-vectorized (G13), double accum ------------------
__global__ __launch_bounds__(256) void wabs_sum_kernel(
    const float* __restrict__ W0, const float* __restrict__ W1,
    const float* __restrict__ W2, const float* __restrict__ W3,
    double* __restrict__ wsum)
{
  const int w   = blockIdx.x >> 6;
  const int blk = blockIdx.x & 63;
  const float* W = (w == 0) ? W0 : (w == 1) ? W1 : (w == 2) ? W2 : W3;
  const float4* W4 = (const float4*)W;
  const int n4 = (C_ * C_) / 4;
  double s = 0.0;
  for (int i = blk * 256 + (int)threadIdx.x; i < n4; i += 64 * 256) {
    float4 v = W4[i];
    s += (double)fabsf(v.x) + (double)fabsf(v.y) +
         (double)fabsf(v.z) + (double)fabsf(v.w);
  }
  __shared__ double sm[256];
  sm[threadIdx.x] = s;
  __syncthreads();
  for (int o = 128; o > 0; o >>= 1) {
    if ((int)threadIdx.x < o) sm[threadIdx.x] += sm[threadIdx.x + o];
    __syncthreads();
  }
  if (threadIdx.x == 0) atomicAdd(&wsum[w], sm[0]);
}

// ---------------- ternary weight quant: float4 load, packed int8x4 store ------------
__global__ __launch_bounds__(256) void wquant_kernel(
    const float* __restrict__ W0, const float* __restrict__ W1,
    const float* __restrict__ W2, const float* __restrict__ W3,
    const double* __restrict__ wsum, int8_t* __restrict__ Wt, float* __restrict__ sw)
{
  const int w = blockIdx.x >> 10;
  const float* W = (w == 0) ? W0 : (w == 1) ? W1 : (w == 2) ? W2 : W3;
  const int n = C_ * C_;
  const int n4 = n / 4;
  const float s = fmaxf((float)(wsum[w] * (1.0 / (double)n)), EPSF);
  const float4* W4 = (const float4*)W;
  uint32_t* dst4 = (uint32_t*)(Wt + (size_t)w * n);
  const int base = (blockIdx.x & 1023) * 256 + (int)threadIdx.x;
  for (int i = base; i < n4; i += 1024 * 256) {
    float4 v = W4[i];
    union { int8_t b[4]; uint32_t u; } pk;
    pk.b[0] = (int8_t)fminf(fmaxf(rintf(v.x / s), -1.f), 1.f);
    pk.b[1] = (int8_t)fminf(fmaxf(rintf(v.y / s), -1.f), 1.f);
    pk.b[2] = (int8_t)fminf(fmaxf(rintf(v.z / s), -1.f), 1.f);
    pk.b[3] = (int8_t)fminf(fmaxf(rintf(v.w / s), -1.f), 1.f);
    dst4[i] = pk.u;
  }
  if (base == 0) sw[w] = s;
}

// ---------------- per-token act_quant of x: float4 load, packed int8x4 store --------
__global__ __launch_bounds__(256) void xquant_kernel(
    const float* __restrict__ x, int8_t* __restrict__ xq, float* __restrict__ sx)
{
  const int r = blockIdx.x;
  const float4* xr = (const float4*)(x + (size_t)r * C_);
  float am = 0.f;
  for (int j = threadIdx.x; j < C_ / 4; j += 256) {
    float4 v = xr[j];
    am = fmaxf(am, fmaxf(fmaxf(fabsf(v.x), fabsf(v.y)),
                         fmaxf(fabsf(v.z), fabsf(v.w))));
  }
  __shared__ float sm[256];
  sm[threadIdx.x] = am;
  __syncthreads();
  for (int o = 128; o > 0; o >>= 1) {
    if ((int)threadIdx.x < o) sm[threadIdx.x] = fmaxf(sm[threadIdx.x], sm[threadIdx.x + o]);
    __syncthreads();
  }
  const float m = fmaxf(sm[0], EPSF);
  const float scale = 127.f / m;
  uint32_t* dst4 = (uint32_t*)(xq + (size_t)r * C_);
  for (int j = threadIdx.x; j < C_ / 4; j += 256) {
    float4 v = xr[j];
    union { int8_t b[4]; uint32_t u; } pk;
    pk.b[0] = (int8_t)fminf(fmaxf(rintf(v.x * scale), -128.f), 127.f);
    pk.b[1] = (int8_t)fminf(fmaxf(rintf(v.y * scale), -128.f), 127.f);
    pk.b[2] = (int8_t)fminf(fmaxf(rintf(v.z * scale), -128.f), 127.f);
    pk.b[3] = (int8_t)fminf(fmaxf(rintf(v.w * scale), -128.f), 127.f);
    dst4[j] = pk.u;
  }
  if (threadIdx.x == 0) sx[r] = m / 127.f;
}

// ---------------- q/k/v projection: i8 MFMA, async-DMA double-buffered LDS ----------
// R6/528.4us form (best measured; counted-vmcnt variants regressed, R7/R8).
__global__ __launch_bounds__(256) void proj_mfma_kernel(
    const int8_t* __restrict__ xq, const float* __restrict__ sx,
    const int8_t* __restrict__ Wt, const float* __restrict__ sw4,
    int8_t* __restrict__ qkv, float* __restrict__ sqkv)
{
  const int h    = blockIdx.x;
  const int r0   = blockIdx.y * 128;
  const int wsel = blockIdx.z;
  const int tid  = (int)threadIdx.x;
  const int wv   = tid >> 6;
  const int lane = tid & 63;
  const int quad = lane >> 4;
  const int l15  = lane & 15;
  const int rh   = wv >> 1, ch = wv & 1;
  const int8_t* Wm = Wt + (size_t)wsel * C_ * C_;

  __shared__ __align__(16) char As[2][8192];   // 512 slots x 16B, swizzled
  __shared__ __align__(16) char Bs[2][8192];
  __shared__ int rmaxs[128];
  if (tid < 128) rmaxs[tid] = 0;

  const int s0a   = wv * 128;
  const int rowA0 = (s0a + lane) >> 2;
  const int qdA0  = ((s0a + lane) & 3) ^ (rowA0 & 3);
  const int rowA1 = (s0a + 64 + lane) >> 2;
  const int qdA1  = ((s0a + 64 + lane) & 3) ^ (rowA1 & 3);

  auto stage = [&](int bf, int k0) {
    dma16(xq + (size_t)(r0 + rowA0) * C_ + k0 + qdA0 * 16, &As[bf][(s0a) * 16]);
    dma16(xq + (size_t)(r0 + rowA1) * C_ + k0 + qdA1 * 16, &As[bf][(s0a + 64) * 16]);
    dma16(Wm + (size_t)(h * 128 + rowA0) * C_ + k0 + qdA0 * 16, &Bs[bf][(s0a) * 16]);
    dma16(Wm + (size_t)(h * 128 + rowA1) * C_ + k0 + qdA1 * 16, &Bs[bf][(s0a + 64) * 16]);
  };

  i32x4 acc[4][4];
  #pragma unroll
  for (int i = 0; i < 4; ++i)
    #pragma unroll
    for (int j = 0; j < 4; ++j) acc[i][j] = i32x4{0, 0, 0, 0};

  stage(0, 0);
  for (int kc = 0; kc < 32; ++kc) {
    __syncthreads();
    if (kc + 1 < 32) stage((kc + 1) & 1, (kc + 1) * 64);
    const char* Ab = As[kc & 1];
    const char* Bb = Bs[kc & 1];
    i32x4 a[4], b[4];
    #pragma unroll
    for (int rt = 0; rt < 4; ++rt) {
      const int row = rh * 64 + rt * 16 + l15;
      a[rt] = *(const i32x4*)(Ab + (row * 4 + (quad ^ (row & 3))) * 16);
    }
    #pragma unroll
    for (int ct = 0; ct < 4; ++ct) {
      const int col = ch * 64 + ct * 16 + l15;
      b[ct] = *(const i32x4*)(Bb + (col * 4 + (quad ^ (col & 3))) * 16);
    }
    #pragma unroll
    for (int rt = 0; rt < 4; ++rt)
      #pragma unroll
      for (int ct = 0; ct < 4; ++ct)
        acc[rt][ct] = mfma_i8(a[rt], b[ct], acc[rt][ct]);
  }

  #pragma unroll
  for (int rt = 0; rt < 4; ++rt)
    #pragma unroll
    for (int r = 0; r < 4; ++r) {
      int m = 0;
      #pragma unroll
      for (int ct = 0; ct < 4; ++ct) {
        int v = acc[rt][ct][r];
        int av = v < 0 ? -v : v;
        m = m > av ? m : av;
      }
      #pragma unroll
      for (int mm = 1; mm < 16; mm <<= 1) {
        int o = __shfl_xor(m, mm, 64);
        m = m > o ? m : o;
      }
      if (l15 == 0) atomicMax(&rmaxs[rh * 64 + rt * 16 + quad * 4 + r], m);
    }
  __syncthreads();

  const float swv = sw4[wsel];
  #pragma unroll
  for (int rt = 0; rt < 4; ++rt)
    #pragma unroll
    for (int r = 0; r < 4; ++r) {
      const int rowl = rh * 64 + rt * 16 + quad * 4 + r;
      const int rglob = r0 + rowl;
      const int mN = rmaxs[rowl];
      const float qscale = (mN > 0) ? 127.f / (float)mN : 0.f;
      const int bb = rglob >> 11;
      const int tt = rglob & (T_ - 1);
      const size_t obase = ((size_t)(bb * H_ + h) * T_ + tt) * D_;
      #pragma unroll
      for (int ct = 0; ct < 4; ++ct) {
        const int col = ch * 64 + ct * 16 + l15;
        float q = rintf((float)acc[rt][ct][r] * qscale);
        q = fminf(fmaxf(q, -128.f), 127.f);
        qkv[(size_t)wsel * R_ * C_ + obase + col] = (int8_t)q;
      }
      if (ch == 0 && l15 == 0) {
        float maxq = (float)mN * sx[rglob] * swv;
        sqkv[(size_t)wsel * R_ * H_ + (size_t)(bb * H_ + h) * T_ + tt] =
            fmaxf(maxq, EPSF) / 127.f;
      }
    }
}

// ---------------- rowmax v2: LDS-staged K, proj-style pipeline (bit-exact) ----------
// R10 post-mortem: standalone rowmax was ~59us (0.58 TOPS, 1.3% of i8 peak) — same
// latency-exposed global-K streaming as old pass 1. v2 applies the measured-proven
// staging recipe: 64-key/8KB K chunks via async dma16, double-buffered, XOR-swizzled
// (linear dest + pre-swizzled src + swizzled read), SHARED by all 4 waves; sk staged
// once (zero global ops in the loop); proj's 1-barrier-per-chunk schedule. Wave w
// owns q-rows [q0+w*16, +16) and scans ALL keys -> no cross-wave reduce. Identical
// integer MFMA products, identical c*sk floats; max is order-independent -> m
// bit-identical.
__global__ __launch_bounds__(256) void rowmax_kernel(
    const int8_t* __restrict__ qq, const int8_t* __restrict__ kq,
    const float* __restrict__ sk, float* __restrict__ rmax)
{
  const int bh  = blockIdx.x;
  const int q0  = blockIdx.y * 64;
  const int tid = (int)threadIdx.x;
  const int w    = tid >> 6;
  const int lane = tid & 63;
  const int quad = lane >> 4;
  const int l15  = lane & 15;

  __shared__ __align__(16) char smem[24576];   // K bufs 2x8KB [0,16384); sks 8KB
  float* sks = (float*)(smem + 16384);

  const int8_t* kq_bh = kq + (size_t)bh * T_ * D_;

  // K staging: chunk cc = 64 keys x 128B = 512 slots x 16B; wave w stages slots
  // [w*128, w*128+128) via 2 dma16 (dest = uniform base + lane*16).
  const int slot0 = w * 128 + lane;
  const int key0  = slot0 >> 3;
  const int src0  = ((slot0 & 7) ^ (key0 & 7)) * 16;
  const int slot1 = w * 128 + 64 + lane;
  const int key1  = slot1 >> 3;
  const int src1  = ((slot1 & 7) ^ (key1 & 7)) * 16;
  auto stageK = [&](int buf, int cc) {
    dma16(kq_bh + (size_t)(cc * 64 + key0) * 128 + src0, smem + buf * 8192 + w * 2048);
    dma16(kq_bh + (size_t)(cc * 64 + key1) * 128 + src1, smem + buf * 8192 + w * 2048 + 1024);
  };

  // sk -> LDS once (2 dma16/wave, 16B/lane)
  {
    const float* skg = sk + (size_t)bh * T_;
    dma16(skg + (w * 2 + 0) * 256 + lane * 4, smem + 16384 + (w * 2 + 0) * 1024);
    dma16(skg + (w * 2 + 1) * 256 + lane * 4, smem + 16384 + (w * 2 + 1) * 1024);
  }
  stageK(0, 0);

  // Q B-frags for this wave's 16 q-rows (q col = l15)
  i32x4 qf[2];
  #pragma unroll
  for (int hf = 0; hf < 2; ++hf)
    qf[hf] = *(const i32x4*)(qq + ((size_t)bh * T_ + q0 + w * 16 + l15) * D_ +
                             hf * 64 + quad * 16);

  float rx[4];
  #pragma unroll
  for (int r = 0; r < 4; ++r) rx[r] = -3e38f;

  for (int cc = 0; cc < 32; ++cc) {
    __syncthreads();                 // drains DMAs for chunk cc (and sk on cc=0)
    if (cc + 1 < 32) stageK((cc + 1) & 1, cc + 1);
    const char* Kb = smem + (cc & 1) * 8192;
    #pragma unroll
    for (int kt = 0; kt < 4; ++kt) {
      const int key = kt * 16 + l15;
      const f32x4 skv = *(const f32x4*)(sks + cc * 64 + kt * 16 + quad * 4);
      const i32x4 ka = *(const i32x4*)(Kb + key * 128 + ((quad ^ (key & 7)) << 4));
      const i32x4 kb = *(const i32x4*)(Kb + key * 128 + (((quad + 4) ^ (key & 7)) << 4));
      i32x4 c = i32x4{0, 0, 0, 0};
      c = mfma_i8(ka, qf[0], c);
      c = mfma_i8(kb, qf[1], c);
      #pragma unroll
      for (int r = 0; r < 4; ++r)
        rx[r] = fmaxf(rx[r], (float)c[r] * skv[r]);
    }
  }

  float m = fmaxf(fmaxf(rx[0], rx[1]), fmaxf(rx[2], rx[3]));
  m = fmaxf(m, __shfl_xor(m, 16, 64));
  m = fmaxf(m, __shfl_xor(m, 32, 64));
  if (quad == 0) rmax[(size_t)bh * T_ + q0 + w * 16 + l15] = m;
}

// ---------------- V dequant+transpose: int8 [bh][t][d] -> PV-fragment layout ---------
__global__ __launch_bounds__(256) void vtrans_kernel(
    const int8_t* __restrict__ vq, const float* __restrict__ sv,
    short* __restrict__ vT)
{
  const int bh = blockIdx.y;
  const int s0 = blockIdx.x * 64;
  const int tid = (int)threadIdx.x;
  __shared__ __align__(16) int8_t Vs[64][144];
  __shared__ float svs[64];
  const int8_t* vbase = vq + ((size_t)bh * T_ + s0) * D_;
  #pragma unroll
  for (int it = 0; it < 2; ++it) {
    int idx = tid + it * 256;
    int row = idx >> 3, seg = idx & 7;
    *(uint4*)(&Vs[row][seg * 16]) = *(const uint4*)(vbase + row * 128 + seg * 16);
  }
  if (tid < 64) svs[tid] = sv[(size_t)bh * T_ + s0 + tid];
  __syncthreads();
  const int d    = tid >> 1;
  const int half = tid & 1;            // which 32-key chunk within this block
  const int kh   = half * 32;
  uint32_t oh[16], ol[16];
  #pragma unroll
  for (int i = 0; i < 32; i += 2) {
    const int k0 = kh + i, k1 = kh + i + 1;
    float v0 = (float)(int)Vs[k0][d] * svs[k0];
    float v1 = (float)(int)Vs[k1][d] * svs[k1];
    short h0 = f2bf(v0), h1 = f2bf(v1);
    short l0 = f2bf(v0 - bf2f(h0)), l1 = f2bf(v1 - bf2f(h1));
    oh[i >> 1] = (uint32_t)(uint16_t)h0 | ((uint32_t)(uint16_t)h1 << 16);
    ol[i >> 1] = (uint32_t)(uint16_t)l0 | ((uint32_t)(uint16_t)l1 << 16);
  }
  const int c = (s0 >> 5) + half;      // global 32-key chunk index (0..63)
  char* out = (char*)vT + ((((size_t)bh * 128 + d) * 64 + (size_t)c) << 7);
  const int par = d & 7;
  #pragma unroll
  for (int g = 0; g < 4; ++g) {
    uint4 hi, lo;
    hi.x = oh[2 * g];     hi.y = oh[2 * g + 1];
    hi.z = oh[2 * g + 8]; hi.w = oh[2 * g + 9];
    lo.x = ol[2 * g];     lo.y = ol[2 * g + 1];
    lo.z = ol[2 * g + 8]; lo.w = ol[2 * g + 9];
    *(uint4*)(out + (((2 * g + par) & 7) << 4))     = hi;
    *(uint4*)(out + (((2 * g + 1 + par) & 7) << 4)) = lo;
  }
}

// ---------------- fused attention v14: pass-2 only (rowmax hoisted) ------------------
// Measured 97.0us (R10), Mfma 38.3 / VALU 47.7. Unchanged.
__global__ __launch_bounds__(256, 2) void attn_mfma_kernel(
    const int8_t* __restrict__ qq, const int8_t* __restrict__ kq,
    const float* __restrict__ sq, const float* __restrict__ sk,
    const short* __restrict__ vT, const float* __restrict__ rmax,
    int8_t* __restrict__ yq, float* __restrict__ sy)
{
  const int bh  = blockIdx.x;
  const int t0  = blockIdx.y * 128;
  const int tid = (int)threadIdx.x;
  const int w    = tid >> 6;           // 4 waves
  const int lane = tid & 63;
  const int quad = lane >> 4;
  const int l15  = lane & 15;

  // LDS: K bufs 3x4KB [0,12288); V bufs 3x16KB [12288,61440); sks [61440,69632)
  __shared__ __align__(16) char smem[69632];
  float* sks = (float*)(smem + 61440);

  const int qrow0 = t0 + 32 * w;

  const int8_t* kq_bh = kq + (size_t)bh * T_ * D_;
  const char*   vb    = (const char*)vT + ((size_t)bh << 20);

  const int kslot = w * 64 + lane;               // 0..255
  const int kkey  = kslot >> 3;                  // 0..31
  const int ksrc  = ((kslot & 7) ^ (kkey & 7)) * 16;
  auto stageK = [&](int buf, int cc) {
    dma16(kq_bh + (size_t)(cc * 32 + kkey) * 128 + ksrc,
          smem + buf * 4096 + (w * 64) * 16);
  };

  const size_t vlane = (size_t)(w * 32 + (lane >> 3)) * 8192 + (size_t)((lane & 7) * 16);
  auto stageV = [&](int buf, int cc) {
    char* dst = smem + 12288 + buf * 16384 + (w * 32) * 128;
    const char* src = vb + vlane + (size_t)cc * 128;
    #pragma unroll
    for (int j = 0; j < 4; ++j)
      dma16(src + (size_t)(j * 8) * 8192, dst + j * 1024);
  };

  {
    const float* skg = sk + (size_t)bh * T_;
    dma16(skg + (w * 2 + 0) * 256 + lane * 4, smem + 61440 + (w * 2 + 0) * 1024);
    dma16(skg + (w * 2 + 1) * 256 + lane * 4, smem + 61440 + (w * 2 + 1) * 1024);
  }
  stageK(0, 0);
  stageV(0, 0);

  i32x4 qf[2][2];
  #pragma unroll
  for (int qt = 0; qt < 2; ++qt)
    #pragma unroll
    for (int hf = 0; hf < 2; ++hf)
      qf[qt][hf] = *(const i32x4*)(qq + ((size_t)bh * T_ + qrow0 + qt * 16 + l15) * D_ +
                                   hf * 64 + quad * 16);
  float f0[2];
  #pragma unroll
  for (int qt = 0; qt < 2; ++qt)
    f0[qt] = sq[(size_t)bh * T_ + qrow0 + qt * 16 + l15] * INV_SQRT_D;

  __syncthreads();   // sks + chunk-0 visible

  // m from hoisted rowmax kernel (bit-identical value); f1/g ops identical to v13.
  float f1[2], g[2];
  #pragma unroll
  for (int qt = 0; qt < 2; ++qt) {
    const float m = rmax[(size_t)bh * T_ + qrow0 + qt * 16 + l15];
    f1[qt] = f0[qt] * LOG2E;
    g[qt]  = LOG2_127 - (m * f0[qt]) * LOG2E;
  }

  // ---- pass 2: quantized softmax (in-register weights) + PV, 64 x 32-key chunks ----
  float zac[2][4] = {};
  f32x4 yacc[2][8];
  #pragma unroll
  for (int qt = 0; qt < 2; ++qt)
    #pragma unroll
    for (int dt = 0; dt < 8; ++dt) yacc[qt][dt] = f32x4{0.f, 0.f, 0.f, 0.f};

  const int seg_hi = ((2 * quad + l15) & 7) << 4;
  const int seg_lo = ((2 * quad + 1 + l15) & 7) << 4;

  int bc = 0, bn = 1;
  for (int c = 0; c < 64; ++c) {
    const int s0k = c * 32;
    if (c + 1 < 64) {
      stageK(bn, c + 1);
      stageV(bn, c + 1);
      asm volatile("s_waitcnt vmcnt(5)" ::: "memory");   // own chunk-c DMAs done
    } else {
      asm volatile("s_waitcnt vmcnt(0)" ::: "memory");
    }
    __builtin_amdgcn_s_barrier();                        // all waves' chunk-c done
    asm volatile("" ::: "memory");                       // pin reads after barrier

    const char* Kb = smem + bc * 4096;
    uint32_t wdw[2][2][2];
    #pragma unroll
    for (int kt = 0; kt < 2; ++kt) {
      const f32x4 skv = *(const f32x4*)(sks + s0k + kt * 16 + quad * 4);
      const int key = kt * 16 + l15;
      const i32x4 ka = *(const i32x4*)(Kb + key * 128 + ((quad ^ (key & 7)) << 4));
      const i32x4 kb = *(const i32x4*)(Kb + key * 128 + (((quad + 4) ^ (key & 7)) << 4));
      #pragma unroll
      for (int qt = 0; qt < 2; ++qt) {
        i32x4 cc = i32x4{0, 0, 0, 0};
        cc = mfma_i8(ka, qf[qt][0], cc);
        cc = mfma_i8(kb, qf[qt][1], cc);
        float wq_[4];
        #pragma unroll
        for (int r = 0; r < 4; ++r) {
          float t = (float)cc[r] * skv[r];
          float wu = fast_exp2(fmaf(t, f1[qt], g[qt]));  // = 127*exp(s-m)
          zac[qt][r] += wu;
          wq_[r] = rintf(wu);                            // integer in [0,127]
        }
        wdw[qt][kt][0] = (__float_as_uint(wq_[0]) >> 16) |
                         (__float_as_uint(wq_[1]) & 0xffff0000u);
        wdw[qt][kt][1] = (__float_as_uint(wq_[2]) >> 16) |
                         (__float_as_uint(wq_[3]) & 0xffff0000u);
      }
    }

    s16x8 wf[2];
    #pragma unroll
    for (int qt = 0; qt < 2; ++qt) {
      u32x4 tw;
      tw[0] = wdw[qt][0][0]; tw[1] = wdw[qt][0][1];
      tw[2] = wdw[qt][1][0]; tw[3] = wdw[qt][1][1];
      wf[qt] = __builtin_bit_cast(s16x8, tw);
    }

    const char* Vc = smem + 12288 + bc * 16384;
    __builtin_amdgcn_s_setprio(1);
    #pragma unroll
    for (int dt = 0; dt < 8; ++dt) {
      const char* rowp = Vc + (dt * 16 + l15) * 128;
      const s16x8 vh = *(const s16x8*)(rowp + seg_hi);
      const s16x8 vl = *(const s16x8*)(rowp + seg_lo);
      yacc[0][dt] = mfma_bf16(wf[0], vh, yacc[0][dt]);
      yacc[0][dt] = mfma_bf16(wf[0], vl, yacc[0][dt]);
      yacc[1][dt] = mfma_bf16(wf[1], vh, yacc[1][dt]);
      yacc[1][dt] = mfma_bf16(wf[1], vl, yacc[1][dt]);
    }
    __builtin_amdgcn_s_setprio(0);

    bc = bn; bn = (bn == 2) ? 0 : bn + 1;
  }

  // ---- epilogue: z reduce over quads, transpose to yacc's row layout, quantize ----
  float zq[2];
  #pragma unroll
  for (int qt = 0; qt < 2; ++qt) {
    float z = (zac[qt][0] + zac[qt][1]) + (zac[qt][2] + zac[qt][3]);
    z += __shfl_xor(z, 16, 64);
    z += __shfl_xor(z, 32, 64);
    zq[qt] = z;                       // all lanes: 127*Z for q = l15
  }

  const int b = bh >> 4;
  const int h = bh & 15;
  #pragma unroll
  for (int qt = 0; qt < 2; ++qt)
    #pragma unroll
    for (int r = 0; r < 4; ++r) {
      const float zr = __shfl(zq[qt], quad * 4 + r, 64);   // z for q = quad*4+r
      float ym = 0.f;
      #pragma unroll
      for (int dt = 0; dt < 8; ++dt) ym = fmaxf(ym, fabsf(yacc[qt][dt][r]));
      #pragma unroll
      for (int mm = 1; mm < 16; mm <<= 1) ym = fmaxf(ym, __shfl_xor(ym, mm, 64));
      const float invz = 1.f / zr;
      const float ymt = fmaxf(ym * invz, EPSF);
      const float fs = 127.f / ymt;
      const int tglob = t0 + 32 * w + qt * 16 + quad * 4 + r;
      const size_t rowbase = ((size_t)(b * T_ + tglob)) * C_ + h * D_;
      #pragma unroll
      for (int dt = 0; dt < 8; ++dt) {
        float yv = yacc[qt][dt][r] * invz;
        float qv = fminf(fmaxf(rintf(yv * fs), -128.f), 127.f);
        yq[rowbase + dt * 16 + l15] = (int8_t)qv;
      }
      if (l15 == 0)
        sy[(size_t)(b * T_ + tglob) * H_ + h] = ymt / 127.f;
    }
}

// ---------------- output projection v2: async-DMA double-buffered (R6 form) ---------
__global__ __launch_bounds__(256) void outproj_mfma_kernel(
    const int8_t* __restrict__ yq, const float* __restrict__ sy,
    const int8_t* __restrict__ Wt, const float* __restrict__ sw4,
    float* __restrict__ outp)
{
  const int n0  = blockIdx.x * 64;
  const int r0  = blockIdx.y * 128;
  const int tid = (int)threadIdx.x;
  const int wv   = tid >> 6;
  const int lane = tid & 63;
  const int quad = lane >> 4;
  const int l15  = lane & 15;
  const int rh   = wv >> 1, ch = wv & 1;
  const int8_t* Wm = Wt + (size_t)3 * C_ * C_;

  __shared__ __align__(16) char As[2][8192];   // 512 slots x 16B, swizzled
  __shared__ __align__(16) char Bs[2][4096];   // 256 slots x 16B, swizzled
  __shared__ float sYs[128][16];
  for (int idx = tid; idx < 128 * 16; idx += 256)
    sYs[idx >> 4][idx & 15] = sy[(size_t)(r0 + (idx >> 4)) * H_ + (idx & 15)];

  const int s0a   = wv * 128;
  const int rowA0 = (s0a + lane) >> 2;
  const int qdA0  = ((s0a + lane) & 3) ^ (rowA0 & 3);
  const int rowA1 = (s0a + 64 + lane) >> 2;
  const int qdA1  = ((s0a + 64 + lane) & 3) ^ (rowA1 & 3);
  const int sb    = wv * 64 + lane;
  const int colB  = sb >> 2;
  const int qdB   = (sb & 3) ^ (colB & 3);

  auto stage = [&](int bf, int k0) {
    dma16(yq + (size_t)(r0 + rowA0) * C_ + k0 + qdA0 * 16, &As[bf][(s0a) * 16]);
    dma16(yq + (size_t)(r0 + rowA1) * C_ + k0 + qdA1 * 16, &As[bf][(s0a + 64) * 16]);
    dma16(Wm + (size_t)(n0 + colB) * C_ + k0 + qdB * 16, &Bs[bf][(wv * 64) * 16]);
  };

  i32x4 iacc[4][2];
  f32x4 facc[4][2];
  #pragma unroll
  for (int i = 0; i < 4; ++i)
    #pragma unroll
    for (int j = 0; j < 2; ++j) { iacc[i][j] = i32x4{0,0,0,0}; facc[i][j] = f32x4{0.f,0.f,0.f,0.f}; }

  stage(0, 0);
  for (int kc = 0; kc < 32; ++kc) {
    __syncthreads();
    if (kc + 1 < 32) stage((kc + 1) & 1, (kc + 1) * 64);
    const char* Ab = As[kc & 1];
    const char* Bb = Bs[kc & 1];
    i32x4 a[4], b[2];
    #pragma unroll
    for (int rt = 0; rt < 4; ++rt) {
      const int row = rh * 64 + rt * 16 + l15;
      a[rt] = *(const i32x4*)(Ab + (row * 4 + (quad ^ (row & 3))) * 16);
    }
    #pragma unroll
    for (int ct = 0; ct < 2; ++ct) {
      const int col = ch * 32 + ct * 16 + l15;
      b[ct] = *(const i32x4*)(Bb + (col * 4 + (quad ^ (col & 3))) * 16);
    }
    #pragma unroll
    for (int rt = 0; rt < 4; ++rt)
      #pragma unroll
      for (int ct = 0; ct < 2; ++ct)
        iacc[rt][ct] = mfma_i8(a[rt], b[ct], iacc[rt][ct]);
    if (kc & 1) {
      const int hd = kc >> 1;
      #pragma unroll
      for (int rt = 0; rt < 4; ++rt)
        #pragma unroll
        for (int r = 0; r < 4; ++r) {
          const float s = sYs[rh * 64 + rt * 16 + quad * 4 + r][hd];
          #pragma unroll
          for (int ct = 0; ct < 2; ++ct)
            facc[rt][ct][r] += (float)iacc[rt][ct][r] * s;
        }
      #pragma unroll
      for (int rt = 0; rt < 4; ++rt)
        #pragma unroll
        for (int ct = 0; ct < 2; ++ct) iacc[rt][ct] = i32x4{0,0,0,0};
    }
  }
  const float swp = sw4[3];
  #pragma unroll
  for (int rt = 0; rt < 4; ++rt)
    #pragma unroll
    for (int r = 0; r < 4; ++r) {
      const int rowl = rh * 64 + rt * 16 + quad * 4 + r;
      #pragma unroll
      for (int ct = 0; ct < 2; ++ct)
        outp[(size_t)(r0 + rowl) * C_ + n0 + ch * 32 + ct * 16 + l15] =
            facc[rt][ct][r] * swp;
    }
}

// ---------------- final per-token act_quant: float4 in/out --------------------------
__global__ __launch_bounds__(256) void final_quant_kernel(
    const float* __restrict__ outp, float* __restrict__ out)
{
  const int r = blockIdx.x;
  const float4* xr = (const float4*)(outp + (size_t)r * C_);
  float am = 0.f;
  for (int j = threadIdx.x; j < C_ / 4; j += 256) {
    float4 v = xr[j];
    am = fmaxf(am, fmaxf(fmaxf(fabsf(v.x), fabsf(v.y)),
                         fmaxf(fabsf(v.z), fabsf(v.w))));
  }
  __shared__ float sm[256];
  sm[threadIdx.x] = am;
  __syncthreads();
  for (int o = 128; o > 0; o >>= 1) {
    if ((int)threadIdx.x < o) sm[threadIdx.x] = fmaxf(sm[threadIdx.x], sm[threadIdx.x + o]);
    __syncthreads();
  }
  const float m = fmaxf(sm[0], EPSF);
  const float scale = 127.f / m;
  const float inv = m / 127.f;
  float4* o4 = (float4*)(out + (size_t)r * C_);
  for (int j = threadIdx.x; j < C_ / 4; j += 256) {
    float4 v = xr[j];
    float4 o;
    o.x = fminf(fmaxf(rintf(v.x * scale), -128.f), 127.f) * inv;
    o.y = fminf(fmaxf(rintf(v.y * scale), -128.f), 127.f) * inv;
    o.z = fminf(fmaxf(rintf(v.z * scale), -128.f), 127.f) * inv;
    o.w = fminf(fmaxf(rintf(v.w * scale), -128.f), 127.f) * inv;
    o4[j] = o;
  }
}

} // namespace

extern "C" void kernel_launch(void* const* d_in, const int* in_sizes, int n_in,
                              void* d_out, int out_size, void* d_ws, size_t ws_size,
                              hipStream_t stream)
{
  (void)in_sizes; (void)n_in; (void)out_size; (void)ws_size;
  const float* x  = (const float*)d_in[0];
  const float* W0 = (const float*)d_in[1];
  const float* W1 = (const float*)d_in[2];
  const float* W2 = (const float*)d_in[3];
  const float* W3 = (const float*)d_in[4];

  char* ws = (char*)d_ws;
  double* wsum = (double*)(ws + OFF_WSUM);
  float*  swv  = (float*) (ws + OFF_SW);
  int8_t* Wt   = (int8_t*)(ws + OFF_WT);
  int8_t* xq   = (int8_t*)(ws + OFF_XQ);
  float*  sx   = (float*) (ws + OFF_SX);
  int8_t* qkv  = (int8_t*)(ws + OFF_QKV);
  float*  sqkv = (float*) (ws + OFF_SQKV);
  int8_t* yqp  = (int8_t*)(ws + OFF_YQ);
  float*  syp  = (float*) (ws + OFF_SY);
  float*  outp = (float*) (ws + OFF_OUTP);
  short*  vT   = (short*) (ws + OFF_VT);           // aliases outp
  float*  rmx  = (float*) (ws + OFF_XQ);           // aliases xq (dead after proj)

  hipMemsetAsync(d_ws, 0, 256, stream);
  hipLaunchKernelGGL(wabs_sum_kernel, dim3(256), dim3(256), 0, stream, W0, W1, W2, W3, wsum);
  hipLaunchKernelGGL(wquant_kernel, dim3(4096), dim3(256), 0, stream, W0, W1, W2, W3, wsum, Wt, swv);
  hipLaunchKernelGGL(xquant_kernel, dim3(R_), dim3(256), 0, stream, x, xq, sx);
  hipLaunchKernelGGL(proj_mfma_kernel, dim3(H_, R_ / 128, 3), dim3(256), 0, stream,
                     xq, sx, Wt, swv, qkv, sqkv);
  hipLaunchKernelGGL(rowmax_kernel, dim3(B_ * H_, T_ / 64), dim3(256), 0, stream,
                     qkv, qkv + (size_t)R_ * C_, sqkv + (size_t)R_ * H_, rmx);
  hipLaunchKernelGGL(vtrans_kernel, dim3(T_ / 64, B_ * H_), dim3(256), 0, stream,
                     qkv + (size_t)2 * R_ * C_, sqkv + (size_t)2 * R_ * H_, vT);
  hipLaunchKernelGGL(attn_mfma_kernel, dim3(B_ * H_, T_ / 128), dim3(256), 0, stream,
                     qkv, qkv + (size_t)R_ * C_,
                     sqkv, sqkv + (size_t)R_ * H_,
                     vT, rmx, yqp, syp);
  hipLaunchKernelGGL(outproj_mfma_kernel, dim3(C_ / 64, R_ / 128), dim3(256), 0, stream,
                     yqp, syp, Wt, swv, outp);
  hipLaunchKernelGGL(final_quant_kernel, dim3(R_), dim3(256), 0, stream, outp, (float*)d_out);
}